// Round 6
// baseline (539.881 us; speedup 1.0000x reference)
//
#include <hip/hip_runtime.h>
#include <math.h>

typedef __attribute__((ext_vector_type(4))) float floatx4;
typedef __attribute__((ext_vector_type(8))) short shortx8;   // 8 bf16
typedef __attribute__((ext_vector_type(4))) short shortx4;   // 4 bf16 (8B)

#define NB 4
#define CC 768
#define WW 2048
#define HH 12
#define DD 64
#define GG 4
#define CG 192
#define HPG 3
#define KS 2                       // attention split-K factor
#define L2E 1.4426950408889634f
#define C18 0.18033688011112043f   // 0.125 * log2(e)
#define MSH 11.541560327111707f    // 8.0 * log2(e)  (fixed softmax shift)

__device__ __forceinline__ float fast_exp2(float x) {
    return __builtin_amdgcn_exp2f(x);   // v_exp_f32 (log2 domain)
}

__device__ __forceinline__ short f2bf(float f) {
    union { float f; unsigned u; } v; v.f = f;
    unsigned r = v.u + 0x7fffu + ((v.u >> 16) & 1u);   // RNE
    return (short)(r >> 16);
}
__device__ __forceinline__ float bf2f(short h) {
    union { unsigned u; float f; } v;
    v.u = ((unsigned)(unsigned short)h) << 16;
    return v.f;
}

template<int CTRL>
__device__ __forceinline__ float dppror(float v) {
    return __int_as_float(__builtin_amdgcn_update_dpp(
        0, __float_as_int(v), CTRL, 0xf, 0xf, false));
}
__device__ __forceinline__ float rsum16(float v) {   // 16-lane DPP-row sum
    v += dppror<0x128>(v);
    v += dppror<0x124>(v);
    v += dppror<0x122>(v);
    v += dppror<0x121>(v);
    return v;
}

// ---------------------------------------------------------------------------
// Prep 1: x [N,C,W] fp32 -> XTh/XTl [N,W,C] bf16 hi/lo (transpose + split).
// ---------------------------------------------------------------------------
__global__ __launch_bounds__(256) void prep_x(
    const float* __restrict__ x, short* __restrict__ XTh, short* __restrict__ XTl)
{
    const int w0 = blockIdx.x * 64;
    const int c0 = blockIdx.y * 64;
    const int n  = blockIdx.z;
    const int tid = threadIdx.x;
    const int w  = tid & 63;
    const int cb = c0 + (tid >> 6) * 16;

    float xv[16];
    #pragma unroll
    for (int j = 0; j < 16; ++j)
        xv[j] = x[((size_t)n * CC + cb + j) * WW + w0 + w];

    shortx8 hi0, hi1, lo0, lo1;
    #pragma unroll
    for (int j = 0; j < 8; ++j) {
        short h0 = f2bf(xv[j]);     hi0[j] = h0; lo0[j] = f2bf(xv[j]     - bf2f(h0));
        short h1 = f2bf(xv[j + 8]); hi1[j] = h1; lo1[j] = f2bf(xv[j + 8] - bf2f(h1));
    }
    const size_t ro = ((size_t)n * WW + w0 + w) * CC + cb;
    *(shortx8*)&XTh[ro]     = hi0;
    *(shortx8*)&XTh[ro + 8] = hi1;
    *(shortx8*)&XTl[ro]     = lo0;
    *(shortx8*)&XTl[ro + 8] = lo1;
}

// ---------------------------------------------------------------------------
// Prep 2: weights fp32 -> bf16 hi/lo, concat [mat][G,CG,CG].
// ---------------------------------------------------------------------------
#define WSZ (GG * CG * CG)   // 147456

__global__ __launch_bounds__(256) void prep_w(
    const float* __restrict__ wq, const float* __restrict__ wk,
    const float* __restrict__ wv, short* __restrict__ Wh, short* __restrict__ Wl)
{
    const int t = blockIdx.x * 256 + threadIdx.x;
    if (t >= WSZ) return;
    const float* src[3] = {wq, wk, wv};
    #pragma unroll
    for (int m = 0; m < 3; ++m) {
        float v = src[m][t];
        short h = f2bf(v);
        Wh[m * WSZ + t] = h;
        Wl[m * WSZ + t] = f2bf(v - bf2f(h));
    }
}

// ---------------------------------------------------------------------------
// Grouped 1x1 conv as bf16 hi/lo MFMA GEMM, one matrix (Q/K/V) per block.
// grid (W/64, G, 3*NB) with z = mat*NB + n.  No LDS, no barriers.
// ---------------------------------------------------------------------------
__global__ __launch_bounds__(256) void qkv_gemm(
    const short* __restrict__ XTh, const short* __restrict__ XTl,
    const short* __restrict__ Wh, const short* __restrict__ Wl,
    const float* __restrict__ bq, const float* __restrict__ bk,
    const float* __restrict__ bv,
    short* __restrict__ Qb, short* __restrict__ Kb, short* __restrict__ Vb)
{
    const int p0   = blockIdx.x * 64;
    const int g    = blockIdx.y;
    const int mat  = blockIdx.z >> 2;
    const int n    = blockIdx.z & 3;
    const int tid  = threadIdx.x;
    const int wid  = __builtin_amdgcn_readfirstlane(tid >> 6);
    const int lane = tid & 63;
    const int l15  = lane & 15;
    const int quad = lane >> 4;
    const int ob   = wid * 48;

    const short* xh = XTh + ((size_t)n * WW + p0 + l15) * CC + g * CG + quad * 8;
    const short* xl = XTl + ((size_t)n * WW + p0 + l15) * CC + g * CG + quad * 8;

    const short* whm = Wh + (size_t)mat * WSZ + ((size_t)g * CG + ob + l15) * CG + quad * 8;
    const short* wlm = Wl + (size_t)mat * WSZ + ((size_t)g * CG + ob + l15) * CG + quad * 8;

    floatx4 acc[3][4];
    #pragma unroll
    for (int mi = 0; mi < 3; ++mi)
        #pragma unroll
        for (int ni = 0; ni < 4; ++ni) acc[mi][ni] = (floatx4)0.0f;

    #pragma unroll
    for (int ks = 0; ks < 6; ++ks) {
        const int k0 = ks * 32;
        shortx8 ah[3], al[3], bh[4], bl[4];
        #pragma unroll
        for (int mi = 0; mi < 3; ++mi) {
            ah[mi] = *(const shortx8*)(whm + (size_t)mi * 16 * CG + k0);
            al[mi] = *(const shortx8*)(wlm + (size_t)mi * 16 * CG + k0);
        }
        #pragma unroll
        for (int ni = 0; ni < 4; ++ni) {
            bh[ni] = *(const shortx8*)(xh + (size_t)ni * 16 * CC + k0);
            bl[ni] = *(const shortx8*)(xl + (size_t)ni * 16 * CC + k0);
        }
        #pragma unroll
        for (int mi = 0; mi < 3; ++mi)
            #pragma unroll
            for (int ni = 0; ni < 4; ++ni) {
                acc[mi][ni] = __builtin_amdgcn_mfma_f32_16x16x32_bf16(ah[mi], bh[ni], acc[mi][ni], 0, 0, 0);
                acc[mi][ni] = __builtin_amdgcn_mfma_f32_16x16x32_bf16(ah[mi], bl[ni], acc[mi][ni], 0, 0, 0);
                acc[mi][ni] = __builtin_amdgcn_mfma_f32_16x16x32_bf16(al[mi], bh[ni], acc[mi][ni], 0, 0, 0);
            }
    }

    const float* bias = (mat == 0) ? bq : (mat == 1) ? bk : bv;
    short* Y = (mat == 0) ? Qb : (mat == 1) ? Kb : Vb;
    #pragma unroll
    for (int mi = 0; mi < 3; ++mi) {
        float4 b4 = *(const float4*)&bias[g * CG + ob + mi * 16 + quad * 4];
        const int o  = ob + mi * 16 + quad * 4;
        const int h  = g * HPG + (o >> 6);
        const int d0 = o & 63;
        const size_t nh = (size_t)n * HH + h;
        #pragma unroll
        for (int ni = 0; ni < 4; ++ni) {
            const int p = p0 + ni * 16 + l15;
            float y0 = acc[mi][ni][0] + b4.x;
            float y1 = acc[mi][ni][1] + b4.y;
            float y2 = acc[mi][ni][2] + b4.z;
            float y3 = acc[mi][ni][3] + b4.w;
            if (mat < 2) {
                shortx4 pk = { f2bf(y0), f2bf(y1), f2bf(y2), f2bf(y3) };
                *(shortx4*)&Y[(nh * WW + p) * DD + d0] = pk;   // [w][d]
            } else {
                const size_t vb = (nh * DD + d0) * WW + p;     // [d][w]
                Y[vb]          = f2bf(y0);
                Y[vb + WW]     = f2bf(y1);
                Y[vb + 2 * WW] = f2bf(y2);
                Y[vb + 3 * WW] = f2bf(y3);
            }
        }
    }
}

// ---------------------------------------------------------------------------
// Split-K attention, latency-optimized:
//  - double-buffered register prefetch (2 k-tiles per loop trip, ~20 global
//    loads in flight per wave)  [R5: VGPR=52 -> serialized loads]
//  - XCD-aware swizzle: 6 (n,h) pairs per XCD -> K/V (3 MB) L2-resident
// grid: 3072 1-D blocks; block 256 (4 waves, 16 q each).
// ---------------------------------------------------------------------------
#define PST 72

__device__ __forceinline__ void load_tile(
    const short* __restrict__ Kbase, const short* __restrict__ Vbase,
    const float* __restrict__ mbase, int k0, int l15, int quad,
    shortx8 (&kf)[4][2], shortx8 (&vf)[4][2], float (&mv2)[4])
{
    #pragma unroll
    for (int jj = 0; jj < 4; ++jj) {
        const short* kp = Kbase + (size_t)(k0 + 16 * jj + l15) * DD + quad * 8;
        kf[jj][0] = *(const shortx8*)kp;
        kf[jj][1] = *(const shortx8*)(kp + 32);
    }
    #pragma unroll
    for (int nn2 = 0; nn2 < 4; ++nn2) {
        const short* vp = Vbase + (size_t)(nn2 * 16 + l15) * WW + k0 + quad * 8;
        vf[nn2][0] = *(const shortx8*)vp;
        vf[nn2][1] = *(const shortx8*)(vp + 32);
    }
    #pragma unroll
    for (int jj = 0; jj < 4; ++jj)
        mv2[jj] = fmaf(mbase[k0 + 16 * jj + l15], L2E, -MSH);
}

__device__ __forceinline__ void compute_tile(
    const shortx8 (&kf)[4][2], const shortx8 (&vf)[4][2], const float (&mv2)[4],
    const shortx8 (&qf)[2], short* __restrict__ Pw,
    floatx4 (&oacc)[4], float (&lst)[4], int l15, int quad)
{
    floatx4 sacc[4];
    #pragma unroll
    for (int jj = 0; jj < 4; ++jj) {
        sacc[jj] = (floatx4)0.0f;
        sacc[jj] = __builtin_amdgcn_mfma_f32_16x16x32_bf16(qf[0], kf[jj][0], sacc[jj], 0, 0, 0);
        sacc[jj] = __builtin_amdgcn_mfma_f32_16x16x32_bf16(qf[1], kf[jj][1], sacc[jj], 0, 0, 0);
    }

    // P = exp2(S * 0.125*log2e + (mask-8)*log2e)
    #pragma unroll
    for (int jj = 0; jj < 4; ++jj) {
        #pragma unroll
        for (int r = 0; r < 4; ++r) {
            float p = fast_exp2(fmaf(sacc[jj][r], C18, mv2[jj]));
            lst[r] += p;
            Pw[(quad * 4 + r) * PST + 16 * jj + l15] = f2bf(p);
        }
    }

    shortx8 pf0 = *(const shortx8*)&Pw[l15 * PST + quad * 8];
    shortx8 pf1 = *(const shortx8*)&Pw[l15 * PST + 32 + quad * 8];

    #pragma unroll
    for (int nn2 = 0; nn2 < 4; ++nn2) {
        oacc[nn2] = __builtin_amdgcn_mfma_f32_16x16x32_bf16(pf0, vf[nn2][0], oacc[nn2], 0, 0, 0);
        oacc[nn2] = __builtin_amdgcn_mfma_f32_16x16x32_bf16(pf1, vf[nn2][1], oacc[nn2], 0, 0, 0);
    }
}

__global__ __launch_bounds__(256, 2) void attn_split(
    const short* __restrict__ Qb, const short* __restrict__ Kb,
    const short* __restrict__ Vb, const float* __restrict__ mask,
    float* __restrict__ Op, float* __restrict__ lp)
{
    __shared__ __align__(16) short Pl[4 * 16 * PST];

    // XCD-aware decode: xcd = lin & 7 (empirical round-robin); 6 (n,h) pairs
    // per XCD so each XCD's K/V working set (~3 MB) stays L2-resident.
    const int lin  = blockIdx.x;
    const int xcd  = lin & 7;
    const int slot = lin >> 3;               // 0..383
    const int pair = xcd * 6 + (slot >> 6);  // 0..47
    const int t64  = slot & 63;
    const int s    = t64 >> 5;
    const int qt   = t64 & 31;
    const int n    = pair / HH;
    const int h    = pair % HH;
    const int q0   = qt * 64;

    const int tid  = threadIdx.x;
    const int wid  = __builtin_amdgcn_readfirstlane(tid >> 6);
    const int lane = tid & 63;
    const int l15  = lane & 15;
    const int quad = lane >> 4;

    const size_t nh = (size_t)n * HH + h;
    const short* Kbase = Kb + nh * WW * DD;   // [key][d]
    const short* Vbase = Vb + nh * DD * WW;   // [d][w]
    const float* mbase = mask + (size_t)n * WW;
    const int ks0  = s * (WW / KS);
    const int kend = ks0 + (WW / KS) - 64;    // last valid tile base (clamp)

    shortx8 qf[2];
    {
        const short* qp = Qb + (nh * WW + q0 + wid * 16 + l15) * DD + quad * 8;
        qf[0] = *(const shortx8*)(qp);
        qf[1] = *(const shortx8*)(qp + 32);
    }

    floatx4 oacc[4];
    #pragma unroll
    for (int nn2 = 0; nn2 < 4; ++nn2) oacc[nn2] = (floatx4)0.0f;
    float lst[4] = {0.f, 0.f, 0.f, 0.f};

    short* Pw = Pl + wid * 16 * PST;

    shortx8 kfA[4][2], vfA[4][2], kfB[4][2], vfB[4][2];
    float mvA[4], mvB[4];

    load_tile(Kbase, Vbase, mbase, ks0, l15, quad, kfA, vfA, mvA);

    for (int kt2 = 0; kt2 < WW / (128 * KS); ++kt2) {
        const int k0e = ks0 + kt2 * 128;
        const int k0o = k0e + 64;
        const int k0n = (k0e + 128 > kend) ? kend : (k0e + 128);  // clamped prefetch

        load_tile(Kbase, Vbase, mbase, k0o, l15, quad, kfB, vfB, mvB);
        compute_tile(kfA, vfA, mvA, qf, Pw, oacc, lst, l15, quad);
        load_tile(Kbase, Vbase, mbase, k0n, l15, quad, kfA, vfA, mvA);
        compute_tile(kfB, vfB, mvB, qf, Pw, oacc, lst, l15, quad);
    }

    // store raw partials: O (fp32, [nh][s][q][d]) and l ([nh][s][q])
    float* obase = Op + ((nh * KS + s) * WW + q0) * DD;
    #pragma unroll
    for (int nn2 = 0; nn2 < 4; ++nn2)
        #pragma unroll
        for (int r = 0; r < 4; ++r)
            obase[(size_t)(wid * 16 + quad * 4 + r) * DD + nn2 * 16 + l15] = oacc[nn2][r];

    #pragma unroll
    for (int r = 0; r < 4; ++r) lst[r] = rsum16(lst[r]);
    if (l15 == 0) {
        float* lbase = lp + (nh * KS + s) * WW + q0;
        #pragma unroll
        for (int r = 0; r < 4; ++r) lbase[wid * 16 + quad * 4 + r] = lst[r];
    }
}

// ---------------------------------------------------------------------------
// Reduce: sum KS partials, normalize, transpose to [N,C,W].
// grid (W/64, H, N), block 256.
// ---------------------------------------------------------------------------
#define RST 65

__global__ __launch_bounds__(256) void attn_reduce(
    const float* __restrict__ Op, const float* __restrict__ lp,
    float* __restrict__ out)
{
    __shared__ float Ol[64 * RST];   // [q][d], stride 65
    __shared__ float linv[64];

    const int q0 = blockIdx.x * 64;
    const int h  = blockIdx.y;
    const int n  = blockIdx.z;
    const int tid = threadIdx.x;
    const size_t nh = (size_t)n * HH + h;

    if (tid < 64) {
        float ls = 0.f;
        #pragma unroll
        for (int s = 0; s < KS; ++s) ls += lp[(nh * KS + s) * WW + q0 + tid];
        linv[tid] = 1.0f / ls;
    }
    __syncthreads();

    #pragma unroll
    for (int it = 0; it < 4; ++it) {
        const int idx = tid + it * 256;        // 64 q x 16 d-groups, dg fast
        const int q  = idx >> 4;
        const int d0 = (idx & 15) * 4;
        floatx4 a = (floatx4)0.0f;
        #pragma unroll
        for (int s = 0; s < KS; ++s)
            a += *(const floatx4*)&Op[(((nh * KS + s) * WW) + q0 + q) * DD + d0];
        a *= linv[q];
        #pragma unroll
        for (int i = 0; i < 4; ++i) Ol[q * RST + d0 + i] = a[i];
    }
    __syncthreads();

    float* obase = out + (nh * DD) * WW + q0;
    #pragma unroll
    for (int it = 0; it < 4; ++it) {
        const int idx = tid + it * 256;        // 64 d x 16 q-groups, qg fast
        const int q4 = (idx & 15) * 4;
        const int d  = idx >> 4;
        floatx4 v;
        #pragma unroll
        for (int i = 0; i < 4; ++i) v[i] = Ol[(q4 + i) * RST + d];
        *(floatx4*)&obase[(size_t)d * WW + q4] = v;
    }
}

// ---------------------------------------------------------------------------
extern "C" void kernel_launch(void* const* d_in, const int* in_sizes, int n_in,
                              void* d_out, int out_size, void* d_ws, size_t ws_size,
                              hipStream_t stream) {
    const float* x    = (const float*)d_in[0];
    const float* mask = (const float*)d_in[1];
    const float* wq   = (const float*)d_in[2];
    const float* bq   = (const float*)d_in[3];
    const float* wk   = (const float*)d_in[4];
    const float* bk   = (const float*)d_in[5];
    const float* wv   = (const float*)d_in[6];
    const float* bv   = (const float*)d_in[7];
    float* out = (float*)d_out;

    const size_t per = (size_t)NB * HH * WW * DD;   // 6,291,456
    short* Qb  = (short*)d_ws;
    short* Kb  = Qb + per;
    short* Vb  = Kb + per;
    // prep region (dead after qkv_gemm):
    short* XTh = Vb + per;
    short* XTl = XTh + per;
    short* Whp = XTl + per;
    short* Wlp = Whp + 3 * WSZ;
    // attention partials overlay the prep region:
    float* Op  = (float*)(Vb + per);                // KS*per fp32
    float* lp  = Op + (size_t)KS * per;             // KS*N*H*W fp32

    hipLaunchKernelGGL(prep_x, dim3(WW / 64, CC / 64, NB), dim3(256), 0, stream,
                       x, XTh, XTl);
    hipLaunchKernelGGL(prep_w, dim3((WSZ + 255) / 256), dim3(256), 0, stream,
                       wq, wk, wv, Whp, Wlp);
    hipLaunchKernelGGL(qkv_gemm, dim3(WW / 64, GG, 3 * NB), dim3(256), 0, stream,
                       XTh, XTl, Whp, Wlp, bq, bk, bv, Qb, Kb, Vb);
    hipLaunchKernelGGL(attn_split, dim3((WW / 64) * KS * HH * NB), dim3(256), 0, stream,
                       Qb, Kb, Vb, mask, Op, lp);
    hipLaunchKernelGGL(attn_reduce, dim3(WW / 64, HH, NB), dim3(256), 0, stream,
                       Op, lp, out);
}

// Round 7
// 513.900 us; speedup vs baseline: 1.0506x; 1.0506x over previous
//
#include <hip/hip_runtime.h>
#include <math.h>

typedef __attribute__((ext_vector_type(4))) float floatx4;
typedef __attribute__((ext_vector_type(8))) short shortx8;   // 8 bf16
typedef __attribute__((ext_vector_type(4))) short shortx4;   // 4 bf16 (8B)

#define NB 4
#define CC 768
#define WW 2048
#define HH 12
#define DD 64
#define GG 4
#define CG 192
#define HPG 3
#define KS 2                       // attention split-K factor
#define L2E 1.4426950408889634f
#define C18 0.18033688011112043f   // 0.125 * log2(e)
#define MSH 11.541560327111707f    // 8.0 * log2(e)  (fixed softmax shift)

__device__ __forceinline__ float fast_exp2(float x) {
    return __builtin_amdgcn_exp2f(x);   // v_exp_f32 (log2 domain)
}

__device__ __forceinline__ short f2bf(float f) {
    union { float f; unsigned u; } v; v.f = f;
    unsigned r = v.u + 0x7fffu + ((v.u >> 16) & 1u);   // RNE
    return (short)(r >> 16);
}
__device__ __forceinline__ float bf2f(short h) {
    union { unsigned u; float f; } v;
    v.u = ((unsigned)(unsigned short)h) << 16;
    return v.f;
}

template<int CTRL>
__device__ __forceinline__ float dppror(float v) {
    return __int_as_float(__builtin_amdgcn_update_dpp(
        0, __float_as_int(v), CTRL, 0xf, 0xf, false));
}
__device__ __forceinline__ float rsum16(float v) {   // 16-lane DPP-row sum
    v += dppror<0x128>(v);
    v += dppror<0x124>(v);
    v += dppror<0x122>(v);
    v += dppror<0x121>(v);
    return v;
}

// ---------------------------------------------------------------------------
// Prep 1: x [N,C,W] fp32 -> XTh/XTl [N,W,C] bf16 hi/lo (transpose + split).
// ---------------------------------------------------------------------------
__global__ __launch_bounds__(256) void prep_x(
    const float* __restrict__ x, short* __restrict__ XTh, short* __restrict__ XTl)
{
    const int w0 = blockIdx.x * 64;
    const int c0 = blockIdx.y * 64;
    const int n  = blockIdx.z;
    const int tid = threadIdx.x;
    const int w  = tid & 63;
    const int cb = c0 + (tid >> 6) * 16;

    float xv[16];
    #pragma unroll
    for (int j = 0; j < 16; ++j)
        xv[j] = x[((size_t)n * CC + cb + j) * WW + w0 + w];

    shortx8 hi0, hi1, lo0, lo1;
    #pragma unroll
    for (int j = 0; j < 8; ++j) {
        short h0 = f2bf(xv[j]);     hi0[j] = h0; lo0[j] = f2bf(xv[j]     - bf2f(h0));
        short h1 = f2bf(xv[j + 8]); hi1[j] = h1; lo1[j] = f2bf(xv[j + 8] - bf2f(h1));
    }
    const size_t ro = ((size_t)n * WW + w0 + w) * CC + cb;
    *(shortx8*)&XTh[ro]     = hi0;
    *(shortx8*)&XTh[ro + 8] = hi1;
    *(shortx8*)&XTl[ro]     = lo0;
    *(shortx8*)&XTl[ro + 8] = lo1;
}

// ---------------------------------------------------------------------------
// Prep 2: weights fp32 -> bf16 hi/lo, concat [mat][G,CG,CG].
// ---------------------------------------------------------------------------
#define WSZ (GG * CG * CG)   // 147456

__global__ __launch_bounds__(256) void prep_w(
    const float* __restrict__ wq, const float* __restrict__ wk,
    const float* __restrict__ wv, short* __restrict__ Wh, short* __restrict__ Wl)
{
    const int t = blockIdx.x * 256 + threadIdx.x;
    if (t >= WSZ) return;
    const float* src[3] = {wq, wk, wv};
    #pragma unroll
    for (int m = 0; m < 3; ++m) {
        float v = src[m][t];
        short h = f2bf(v);
        Wh[m * WSZ + t] = h;
        Wl[m * WSZ + t] = f2bf(v - bf2f(h));
    }
}

// ---------------------------------------------------------------------------
// Grouped 1x1 conv as bf16 hi/lo MFMA GEMM, one matrix (Q/K/V) per block.
// grid (W/64, G, 3*NB) with z = mat*NB + n.  No LDS, no barriers.
// ---------------------------------------------------------------------------
__global__ __launch_bounds__(256) void qkv_gemm(
    const short* __restrict__ XTh, const short* __restrict__ XTl,
    const short* __restrict__ Wh, const short* __restrict__ Wl,
    const float* __restrict__ bq, const float* __restrict__ bk,
    const float* __restrict__ bv,
    short* __restrict__ Qb, short* __restrict__ Kb, short* __restrict__ Vb)
{
    const int p0   = blockIdx.x * 64;
    const int g    = blockIdx.y;
    const int mat  = blockIdx.z >> 2;
    const int n    = blockIdx.z & 3;
    const int tid  = threadIdx.x;
    const int wid  = __builtin_amdgcn_readfirstlane(tid >> 6);
    const int lane = tid & 63;
    const int l15  = lane & 15;
    const int quad = lane >> 4;
    const int ob   = wid * 48;

    const short* xh = XTh + ((size_t)n * WW + p0 + l15) * CC + g * CG + quad * 8;
    const short* xl = XTl + ((size_t)n * WW + p0 + l15) * CC + g * CG + quad * 8;

    const short* whm = Wh + (size_t)mat * WSZ + ((size_t)g * CG + ob + l15) * CG + quad * 8;
    const short* wlm = Wl + (size_t)mat * WSZ + ((size_t)g * CG + ob + l15) * CG + quad * 8;

    floatx4 acc[3][4];
    #pragma unroll
    for (int mi = 0; mi < 3; ++mi)
        #pragma unroll
        for (int ni = 0; ni < 4; ++ni) acc[mi][ni] = (floatx4)0.0f;

    #pragma unroll
    for (int ks = 0; ks < 6; ++ks) {
        const int k0 = ks * 32;
        shortx8 ah[3], al[3], bh[4], bl[4];
        #pragma unroll
        for (int mi = 0; mi < 3; ++mi) {
            ah[mi] = *(const shortx8*)(whm + (size_t)mi * 16 * CG + k0);
            al[mi] = *(const shortx8*)(wlm + (size_t)mi * 16 * CG + k0);
        }
        #pragma unroll
        for (int ni = 0; ni < 4; ++ni) {
            bh[ni] = *(const shortx8*)(xh + (size_t)ni * 16 * CC + k0);
            bl[ni] = *(const shortx8*)(xl + (size_t)ni * 16 * CC + k0);
        }
        #pragma unroll
        for (int mi = 0; mi < 3; ++mi)
            #pragma unroll
            for (int ni = 0; ni < 4; ++ni) {
                acc[mi][ni] = __builtin_amdgcn_mfma_f32_16x16x32_bf16(ah[mi], bh[ni], acc[mi][ni], 0, 0, 0);
                acc[mi][ni] = __builtin_amdgcn_mfma_f32_16x16x32_bf16(ah[mi], bl[ni], acc[mi][ni], 0, 0, 0);
                acc[mi][ni] = __builtin_amdgcn_mfma_f32_16x16x32_bf16(al[mi], bh[ni], acc[mi][ni], 0, 0, 0);
            }
    }

    const float* bias = (mat == 0) ? bq : (mat == 1) ? bk : bv;
    short* Y = (mat == 0) ? Qb : (mat == 1) ? Kb : Vb;
    #pragma unroll
    for (int mi = 0; mi < 3; ++mi) {
        float4 b4 = *(const float4*)&bias[g * CG + ob + mi * 16 + quad * 4];
        const int o  = ob + mi * 16 + quad * 4;
        const int h  = g * HPG + (o >> 6);
        const int d0 = o & 63;
        const size_t nh = (size_t)n * HH + h;
        #pragma unroll
        for (int ni = 0; ni < 4; ++ni) {
            const int p = p0 + ni * 16 + l15;
            float y0 = acc[mi][ni][0] + b4.x;
            float y1 = acc[mi][ni][1] + b4.y;
            float y2 = acc[mi][ni][2] + b4.z;
            float y3 = acc[mi][ni][3] + b4.w;
            if (mat < 2) {
                shortx4 pk = { f2bf(y0), f2bf(y1), f2bf(y2), f2bf(y3) };
                *(shortx4*)&Y[(nh * WW + p) * DD + d0] = pk;   // [w][d]
            } else {
                const size_t vb = (nh * DD + d0) * WW + p;     // [d][w]
                Y[vb]          = f2bf(y0);
                Y[vb + WW]     = f2bf(y1);
                Y[vb + 2 * WW] = f2bf(y2);
                Y[vb + 3 * WW] = f2bf(y3);
            }
        }
    }
}

// ---------------------------------------------------------------------------
// Split-K attention, latency-optimized:
//  - XCD-aware swizzle (R6: FETCH 104->18.5 MB, keep)
//  - register double-buffer ENFORCED by sched_barrier(0) fences: R6's VGPR=80
//    showed the compiler sank prefetch loads to uses; fences forbid that, so
//    all 16 next-tile loads stay in flight across current-tile compute.
//  - mask pre-transformed & staged in LDS once per block (off critical path)
// grid: 3072 1-D blocks; block 256 (4 waves, 16 q each).
// ---------------------------------------------------------------------------
#define PST 72

__device__ __forceinline__ void sfence() { __builtin_amdgcn_sched_barrier(0); }

__device__ __forceinline__ void load_tile(
    const short* __restrict__ Kbase, const short* __restrict__ Vbase,
    const float* __restrict__ mlds, int k0rel, int k0, int l15, int quad,
    shortx8 (&kf)[4][2], shortx8 (&vf)[4][2], float (&mv2)[4])
{
    #pragma unroll
    for (int jj = 0; jj < 4; ++jj) {
        const short* kp = Kbase + (size_t)(k0 + 16 * jj + l15) * DD + quad * 8;
        kf[jj][0] = *(const shortx8*)kp;
        kf[jj][1] = *(const shortx8*)(kp + 32);
    }
    #pragma unroll
    for (int nn2 = 0; nn2 < 4; ++nn2) {
        const short* vp = Vbase + (size_t)(nn2 * 16 + l15) * WW + k0 + quad * 8;
        vf[nn2][0] = *(const shortx8*)vp;
        vf[nn2][1] = *(const shortx8*)(vp + 32);
    }
    #pragma unroll
    for (int jj = 0; jj < 4; ++jj)
        mv2[jj] = mlds[k0rel + 16 * jj + l15];   // pre-transformed, LDS
}

__device__ __forceinline__ void compute_tile(
    const shortx8 (&kf)[4][2], const shortx8 (&vf)[4][2], const float (&mv2)[4],
    const shortx8 (&qf)[2], short* __restrict__ Pw,
    floatx4 (&oacc)[4], float (&lst)[4], int l15, int quad)
{
    floatx4 sacc[4];
    #pragma unroll
    for (int jj = 0; jj < 4; ++jj) {
        sacc[jj] = (floatx4)0.0f;
        sacc[jj] = __builtin_amdgcn_mfma_f32_16x16x32_bf16(qf[0], kf[jj][0], sacc[jj], 0, 0, 0);
        sacc[jj] = __builtin_amdgcn_mfma_f32_16x16x32_bf16(qf[1], kf[jj][1], sacc[jj], 0, 0, 0);
    }

    // P = exp2(S * 0.125*log2e + (mask-8)*log2e)
    #pragma unroll
    for (int jj = 0; jj < 4; ++jj) {
        #pragma unroll
        for (int r = 0; r < 4; ++r) {
            float p = fast_exp2(fmaf(sacc[jj][r], C18, mv2[jj]));
            lst[r] += p;
            Pw[(quad * 4 + r) * PST + 16 * jj + l15] = f2bf(p);
        }
    }

    shortx8 pf0 = *(const shortx8*)&Pw[l15 * PST + quad * 8];
    shortx8 pf1 = *(const shortx8*)&Pw[l15 * PST + 32 + quad * 8];

    #pragma unroll
    for (int nn2 = 0; nn2 < 4; ++nn2) {
        oacc[nn2] = __builtin_amdgcn_mfma_f32_16x16x32_bf16(pf0, vf[nn2][0], oacc[nn2], 0, 0, 0);
        oacc[nn2] = __builtin_amdgcn_mfma_f32_16x16x32_bf16(pf1, vf[nn2][1], oacc[nn2], 0, 0, 0);
    }
}

__global__ __launch_bounds__(256, 2) void attn_split(
    const short* __restrict__ Qb, const short* __restrict__ Kb,
    const short* __restrict__ Vb, const float* __restrict__ mask,
    float* __restrict__ Op, float* __restrict__ lp)
{
    __shared__ __align__(16) short Pl[4 * 16 * PST];
    __shared__ __align__(16) float Ml[WW / KS];     // 4 KB, pre-transformed mask

    // XCD-aware decode: xcd = lin & 7; 6 (n,h) pairs per XCD -> K/V (~3 MB)
    // stays L2-resident (R6 verified: FETCH 104 -> 18.5 MB).
    const int lin  = blockIdx.x;
    const int xcd  = lin & 7;
    const int slot = lin >> 3;               // 0..383
    const int pair = xcd * 6 + (slot >> 6);  // 0..47
    const int t64  = slot & 63;
    const int s    = t64 >> 5;
    const int qt   = t64 & 31;
    const int n    = pair / HH;
    const int h    = pair % HH;
    const int q0   = qt * 64;

    const int tid  = threadIdx.x;
    const int wid  = __builtin_amdgcn_readfirstlane(tid >> 6);
    const int lane = tid & 63;
    const int l15  = lane & 15;
    const int quad = lane >> 4;

    const size_t nh = (size_t)n * HH + h;
    const short* Kbase = Kb + nh * WW * DD;   // [key][d]
    const short* Vbase = Vb + nh * DD * WW;   // [d][w]
    const int ks0  = s * (WW / KS);
    const int kend = ks0 + (WW / KS) - 64;    // last valid tile base (clamp)

    // stage pre-transformed mask (mask*log2e - 8*log2e) once
    {
        const float* mbase = mask + (size_t)n * WW + ks0;
        #pragma unroll
        for (int i = 0; i < (WW / KS) / 256; ++i)
            Ml[tid + i * 256] = fmaf(mbase[tid + i * 256], L2E, -MSH);
    }

    shortx8 qf[2];
    {
        const short* qp = Qb + (nh * WW + q0 + wid * 16 + l15) * DD + quad * 8;
        qf[0] = *(const shortx8*)(qp);
        qf[1] = *(const shortx8*)(qp + 32);
    }
    __syncthreads();

    floatx4 oacc[4];
    #pragma unroll
    for (int nn2 = 0; nn2 < 4; ++nn2) oacc[nn2] = (floatx4)0.0f;
    float lst[4] = {0.f, 0.f, 0.f, 0.f};

    short* Pw = Pl + wid * 16 * PST;

    shortx8 kfA[4][2], vfA[4][2], kfB[4][2], vfB[4][2];
    float mvA[4], mvB[4];

    load_tile(Kbase, Vbase, Ml, 0, ks0, l15, quad, kfA, vfA, mvA);
    sfence();

    for (int kt2 = 0; kt2 < WW / (128 * KS); ++kt2) {
        const int k0e = ks0 + kt2 * 128;
        const int k0o = k0e + 64;
        const int k0n = (k0e + 128 > kend) ? kend : (k0e + 128);  // clamped prefetch

        load_tile(Kbase, Vbase, Ml, k0o - ks0, k0o, l15, quad, kfB, vfB, mvB);
        sfence();
        compute_tile(kfA, vfA, mvA, qf, Pw, oacc, lst, l15, quad);
        sfence();
        load_tile(Kbase, Vbase, Ml, k0n - ks0, k0n, l15, quad, kfA, vfA, mvA);
        sfence();
        compute_tile(kfB, vfB, mvB, qf, Pw, oacc, lst, l15, quad);
        sfence();
    }

    // store raw partials: O (fp32, [nh][s][q][d]) and l ([nh][s][q])
    float* obase = Op + ((nh * KS + s) * WW + q0) * DD;
    #pragma unroll
    for (int nn2 = 0; nn2 < 4; ++nn2)
        #pragma unroll
        for (int r = 0; r < 4; ++r)
            obase[(size_t)(wid * 16 + quad * 4 + r) * DD + nn2 * 16 + l15] = oacc[nn2][r];

    #pragma unroll
    for (int r = 0; r < 4; ++r) lst[r] = rsum16(lst[r]);
    if (l15 == 0) {
        float* lbase = lp + (nh * KS + s) * WW + q0;
        #pragma unroll
        for (int r = 0; r < 4; ++r) lbase[wid * 16 + quad * 4 + r] = lst[r];
    }
}

// ---------------------------------------------------------------------------
// Reduce: sum KS partials, normalize, transpose to [N,C,W].
// grid (W/64, H, N), block 256.
// ---------------------------------------------------------------------------
#define RST 65

__global__ __launch_bounds__(256) void attn_reduce(
    const float* __restrict__ Op, const float* __restrict__ lp,
    float* __restrict__ out)
{
    __shared__ float Ol[64 * RST];   // [q][d], stride 65
    __shared__ float linv[64];

    const int q0 = blockIdx.x * 64;
    const int h  = blockIdx.y;
    const int n  = blockIdx.z;
    const int tid = threadIdx.x;
    const size_t nh = (size_t)n * HH + h;

    if (tid < 64) {
        float ls = 0.f;
        #pragma unroll
        for (int s = 0; s < KS; ++s) ls += lp[(nh * KS + s) * WW + q0 + tid];
        linv[tid] = 1.0f / ls;
    }
    __syncthreads();

    #pragma unroll
    for (int it = 0; it < 4; ++it) {
        const int idx = tid + it * 256;        // 64 q x 16 d-groups, dg fast
        const int q  = idx >> 4;
        const int d0 = (idx & 15) * 4;
        floatx4 a = (floatx4)0.0f;
        #pragma unroll
        for (int s = 0; s < KS; ++s)
            a += *(const floatx4*)&Op[(((nh * KS + s) * WW) + q0 + q) * DD + d0];
        a *= linv[q];
        #pragma unroll
        for (int i = 0; i < 4; ++i) Ol[q * RST + d0 + i] = a[i];
    }
    __syncthreads();

    float* obase = out + (nh * DD) * WW + q0;
    #pragma unroll
    for (int it = 0; it < 4; ++it) {
        const int idx = tid + it * 256;        // 64 d x 16 q-groups, qg fast
        const int q4 = (idx & 15) * 4;
        const int d  = idx >> 4;
        floatx4 v;
        #pragma unroll
        for (int i = 0; i < 4; ++i) v[i] = Ol[(q4 + i) * RST + d];
        *(floatx4*)&obase[(size_t)d * WW + q4] = v;
    }
}

// ---------------------------------------------------------------------------
extern "C" void kernel_launch(void* const* d_in, const int* in_sizes, int n_in,
                              void* d_out, int out_size, void* d_ws, size_t ws_size,
                              hipStream_t stream) {
    const float* x    = (const float*)d_in[0];
    const float* mask = (const float*)d_in[1];
    const float* wq   = (const float*)d_in[2];
    const float* bq   = (const float*)d_in[3];
    const float* wk   = (const float*)d_in[4];
    const float* bk   = (const float*)d_in[5];
    const float* wv   = (const float*)d_in[6];
    const float* bv   = (const float*)d_in[7];
    float* out = (float*)d_out;

    const size_t per = (size_t)NB * HH * WW * DD;   // 6,291,456
    short* Qb  = (short*)d_ws;
    short* Kb  = Qb + per;
    short* Vb  = Kb + per;
    // prep region (dead after qkv_gemm):
    short* XTh = Vb + per;
    short* XTl = XTh + per;
    short* Whp = XTl + per;
    short* Wlp = Whp + 3 * WSZ;
    // attention partials overlay the prep region:
    float* Op  = (float*)(Vb + per);                // KS*per fp32
    float* lp  = Op + (size_t)KS * per;             // KS*N*H*W fp32

    hipLaunchKernelGGL(prep_x, dim3(WW / 64, CC / 64, NB), dim3(256), 0, stream,
                       x, XTh, XTl);
    hipLaunchKernelGGL(prep_w, dim3((WSZ + 255) / 256), dim3(256), 0, stream,
                       wq, wk, wv, Whp, Wlp);
    hipLaunchKernelGGL(qkv_gemm, dim3(WW / 64, GG, 3 * NB), dim3(256), 0, stream,
                       XTh, XTl, Whp, Wlp, bq, bk, bv, Qb, Kb, Vb);
    hipLaunchKernelGGL(attn_split, dim3((WW / 64) * KS * HH * NB), dim3(256), 0, stream,
                       Qb, Kb, Vb, mask, Op, lp);
    hipLaunchKernelGGL(attn_reduce, dim3(WW / 64, HH, NB), dim3(256), 0, stream,
                       Op, lp, out);
}

// Round 8
// 262.257 us; speedup vs baseline: 2.0586x; 1.9595x over previous
//
#include <hip/hip_runtime.h>
#include <math.h>

typedef __attribute__((ext_vector_type(4))) float floatx4;
typedef __attribute__((ext_vector_type(8))) short shortx8;   // 8 bf16
typedef __attribute__((ext_vector_type(4))) short shortx4;   // 4 bf16 (8B)

#define NB 4
#define CC 768
#define WW 2048
#define HH 12
#define DD 64
#define GG 4
#define CG 192
#define HPG 3
#define KS 2                       // attention split-K factor
#define L2E 1.4426950408889634f
#define C18 0.18033688011112043f   // 0.125 * log2(e)
#define MSH 11.541560327111707f    // 8.0 * log2(e)  (fixed softmax shift)

__device__ __forceinline__ float fast_exp2(float x) {
    return __builtin_amdgcn_exp2f(x);   // v_exp_f32 (log2 domain)
}

__device__ __forceinline__ short f2bf(float f) {
    union { float f; unsigned u; } v; v.f = f;
    unsigned r = v.u + 0x7fffu + ((v.u >> 16) & 1u);   // RNE
    return (short)(r >> 16);
}
__device__ __forceinline__ float bf2f(short h) {
    union { unsigned u; float f; } v;
    v.u = ((unsigned)(unsigned short)h) << 16;
    return v.f;
}

template<int CTRL>
__device__ __forceinline__ float dppror(float v) {
    return __int_as_float(__builtin_amdgcn_update_dpp(
        0, __float_as_int(v), CTRL, 0xf, 0xf, false));
}
__device__ __forceinline__ float rsum16(float v) {   // 16-lane DPP-row sum
    v += dppror<0x128>(v);
    v += dppror<0x124>(v);
    v += dppror<0x122>(v);
    v += dppror<0x121>(v);
    return v;
}

// async global->LDS, 16B per lane; lds base must be wave-uniform
__device__ __forceinline__ void gl_lds16(const void* g, void* l) {
    __builtin_amdgcn_global_load_lds(
        (const __attribute__((address_space(1))) unsigned int*)g,
        (__attribute__((address_space(3))) unsigned int*)l, 16, 0, 0);
}

// ---------------------------------------------------------------------------
// Prep 1: x [N,C,W] fp32 -> XTh/XTl [N,W,C] bf16 hi/lo (transpose + split).
// ---------------------------------------------------------------------------
__global__ __launch_bounds__(256) void prep_x(
    const float* __restrict__ x, short* __restrict__ XTh, short* __restrict__ XTl)
{
    const int w0 = blockIdx.x * 64;
    const int c0 = blockIdx.y * 64;
    const int n  = blockIdx.z;
    const int tid = threadIdx.x;
    const int w  = tid & 63;
    const int cb = c0 + (tid >> 6) * 16;

    float xv[16];
    #pragma unroll
    for (int j = 0; j < 16; ++j)
        xv[j] = x[((size_t)n * CC + cb + j) * WW + w0 + w];

    shortx8 hi0, hi1, lo0, lo1;
    #pragma unroll
    for (int j = 0; j < 8; ++j) {
        short h0 = f2bf(xv[j]);     hi0[j] = h0; lo0[j] = f2bf(xv[j]     - bf2f(h0));
        short h1 = f2bf(xv[j + 8]); hi1[j] = h1; lo1[j] = f2bf(xv[j + 8] - bf2f(h1));
    }
    const size_t ro = ((size_t)n * WW + w0 + w) * CC + cb;
    *(shortx8*)&XTh[ro]     = hi0;
    *(shortx8*)&XTh[ro + 8] = hi1;
    *(shortx8*)&XTl[ro]     = lo0;
    *(shortx8*)&XTl[ro + 8] = lo1;
}

// ---------------------------------------------------------------------------
// Prep 2: weights fp32 -> bf16 hi/lo, concat [mat][G,CG,CG].
// ---------------------------------------------------------------------------
#define WSZ (GG * CG * CG)   // 147456

__global__ __launch_bounds__(256) void prep_w(
    const float* __restrict__ wq, const float* __restrict__ wk,
    const float* __restrict__ wv, short* __restrict__ Wh, short* __restrict__ Wl)
{
    const int t = blockIdx.x * 256 + threadIdx.x;
    if (t >= WSZ) return;
    const float* src[3] = {wq, wk, wv};
    #pragma unroll
    for (int m = 0; m < 3; ++m) {
        float v = src[m][t];
        short h = f2bf(v);
        Wh[m * WSZ + t] = h;
        Wl[m * WSZ + t] = f2bf(v - bf2f(h));
    }
}

// ---------------------------------------------------------------------------
// Grouped 1x1 conv as bf16 hi/lo MFMA GEMM, one matrix (Q/K/V) per block.
// grid (W/64, G, 3*NB) with z = mat*NB + n.  No LDS, no barriers.
// ---------------------------------------------------------------------------
__global__ __launch_bounds__(256) void qkv_gemm(
    const short* __restrict__ XTh, const short* __restrict__ XTl,
    const short* __restrict__ Wh, const short* __restrict__ Wl,
    const float* __restrict__ bq, const float* __restrict__ bk,
    const float* __restrict__ bv,
    short* __restrict__ Qb, short* __restrict__ Kb, short* __restrict__ Vb)
{
    const int p0   = blockIdx.x * 64;
    const int g    = blockIdx.y;
    const int mat  = blockIdx.z >> 2;
    const int n    = blockIdx.z & 3;
    const int tid  = threadIdx.x;
    const int wid  = __builtin_amdgcn_readfirstlane(tid >> 6);
    const int lane = tid & 63;
    const int l15  = lane & 15;
    const int quad = lane >> 4;
    const int ob   = wid * 48;

    const short* xh = XTh + ((size_t)n * WW + p0 + l15) * CC + g * CG + quad * 8;
    const short* xl = XTl + ((size_t)n * WW + p0 + l15) * CC + g * CG + quad * 8;

    const short* whm = Wh + (size_t)mat * WSZ + ((size_t)g * CG + ob + l15) * CG + quad * 8;
    const short* wlm = Wl + (size_t)mat * WSZ + ((size_t)g * CG + ob + l15) * CG + quad * 8;

    floatx4 acc[3][4];
    #pragma unroll
    for (int mi = 0; mi < 3; ++mi)
        #pragma unroll
        for (int ni = 0; ni < 4; ++ni) acc[mi][ni] = (floatx4)0.0f;

    #pragma unroll
    for (int ks = 0; ks < 6; ++ks) {
        const int k0 = ks * 32;
        shortx8 ah[3], al[3], bh[4], bl[4];
        #pragma unroll
        for (int mi = 0; mi < 3; ++mi) {
            ah[mi] = *(const shortx8*)(whm + (size_t)mi * 16 * CG + k0);
            al[mi] = *(const shortx8*)(wlm + (size_t)mi * 16 * CG + k0);
        }
        #pragma unroll
        for (int ni = 0; ni < 4; ++ni) {
            bh[ni] = *(const shortx8*)(xh + (size_t)ni * 16 * CC + k0);
            bl[ni] = *(const shortx8*)(xl + (size_t)ni * 16 * CC + k0);
        }
        #pragma unroll
        for (int mi = 0; mi < 3; ++mi)
            #pragma unroll
            for (int ni = 0; ni < 4; ++ni) {
                acc[mi][ni] = __builtin_amdgcn_mfma_f32_16x16x32_bf16(ah[mi], bh[ni], acc[mi][ni], 0, 0, 0);
                acc[mi][ni] = __builtin_amdgcn_mfma_f32_16x16x32_bf16(ah[mi], bl[ni], acc[mi][ni], 0, 0, 0);
                acc[mi][ni] = __builtin_amdgcn_mfma_f32_16x16x32_bf16(al[mi], bh[ni], acc[mi][ni], 0, 0, 0);
            }
    }

    const float* bias = (mat == 0) ? bq : (mat == 1) ? bk : bv;
    short* Y = (mat == 0) ? Qb : (mat == 1) ? Kb : Vb;
    #pragma unroll
    for (int mi = 0; mi < 3; ++mi) {
        float4 b4 = *(const float4*)&bias[g * CG + ob + mi * 16 + quad * 4];
        const int o  = ob + mi * 16 + quad * 4;
        const int h  = g * HPG + (o >> 6);
        const int d0 = o & 63;
        const size_t nh = (size_t)n * HH + h;
        #pragma unroll
        for (int ni = 0; ni < 4; ++ni) {
            const int p = p0 + ni * 16 + l15;
            float y0 = acc[mi][ni][0] + b4.x;
            float y1 = acc[mi][ni][1] + b4.y;
            float y2 = acc[mi][ni][2] + b4.z;
            float y3 = acc[mi][ni][3] + b4.w;
            if (mat < 2) {
                shortx4 pk = { f2bf(y0), f2bf(y1), f2bf(y2), f2bf(y3) };
                *(shortx4*)&Y[(nh * WW + p) * DD + d0] = pk;   // [w][d]
            } else {
                const size_t vb = (nh * DD + d0) * WW + p;     // [d][w]
                Y[vb]          = f2bf(y0);
                Y[vb + WW]     = f2bf(y1);
                Y[vb + 2 * WW] = f2bf(y2);
                Y[vb + 3 * WW] = f2bf(y3);
            }
        }
    }
}

// ---------------------------------------------------------------------------
// Split-K attention, LDS-staged (m97 pattern):
//  - K/V tiles staged to LDS ONCE per block via global_load_lds width=16
//    (R5-R7 were bound by per-wave 16-line gathers, 4x redundant across waves)
//  - XOR source-swizzle (c ^= r&7) so the fixed contiguous LDS layout reads
//    back as conflict-free ds_read_b128 fragments (2-way only = free)
//  - XCD-aware swizzle kept (R6: FETCH 104 -> 18.5 MB)
// grid: 3072 1-D blocks; block 256 (4 waves, 16 q each). LDS 29.3 KB.
// ---------------------------------------------------------------------------
#define PST 72

__global__ __launch_bounds__(256) void attn_split(
    const short* __restrict__ Qb, const short* __restrict__ Kb,
    const short* __restrict__ Vb, const float* __restrict__ mask,
    float* __restrict__ Op, float* __restrict__ lp)
{
    __shared__ __align__(16) short Ks_l[64 * 64];   // 8 KB  [key][d] swizzled
    __shared__ __align__(16) short Vs_l[64 * 64];   // 8 KB  [d][key] swizzled
    __shared__ __align__(16) short Pl[4 * 16 * PST];// 9.2 KB
    __shared__ __align__(16) float Ml[WW / KS];     // 4 KB pre-transformed mask

    // XCD-aware decode: xcd = lin & 7; 6 (n,h) pairs per XCD.
    const int lin  = blockIdx.x;
    const int xcd  = lin & 7;
    const int slot = lin >> 3;               // 0..383
    const int pair = xcd * 6 + (slot >> 6);  // 0..47
    const int t64  = slot & 63;
    const int s    = t64 >> 5;
    const int qt   = t64 & 31;
    const int n    = pair / HH;
    const int h    = pair % HH;
    const int q0   = qt * 64;

    const int tid  = threadIdx.x;
    const int wid  = __builtin_amdgcn_readfirstlane(tid >> 6);
    const int lane = tid & 63;
    const int l15  = lane & 15;
    const int quad = lane >> 4;

    const size_t nh = (size_t)n * HH + h;
    const short* Kbase = Kb + nh * WW * DD;   // [key][d]
    const short* Vbase = Vb + nh * DD * WW;   // [d][w]
    const int ks0 = s * (WW / KS);

    // stage pre-transformed mask (mask*log2e - 8*log2e) once
    {
        const float* mbase = mask + (size_t)n * WW + ks0;
        #pragma unroll
        for (int i = 0; i < (WW / KS) / 256; ++i)
            Ml[tid + i * 256] = fmaf(mbase[tid + i * 256], L2E, -MSH);
    }

    shortx8 qf[2];
    {
        const short* qp = Qb + (nh * WW + q0 + wid * 16 + l15) * DD + quad * 8;
        qf[0] = *(const shortx8*)(qp);
        qf[1] = *(const shortx8*)(qp + 32);
    }

    floatx4 oacc[4];
    #pragma unroll
    for (int nn2 = 0; nn2 < 4; ++nn2) oacc[nn2] = (floatx4)0.0f;
    float lst[4] = {0.f, 0.f, 0.f, 0.f};

    short* Pw = Pl + wid * 16 * PST;

    for (int kt = 0; kt < WW / (64 * KS); ++kt) {
        const int k0 = ks0 + kt * 64;

        // ---- stage K/V tile: wave wid covers rows [wid*16, wid*16+16) ----
        // LDS slot (r, sc) holds global chunk (r, sc ^ (r&7)); lane i of a
        // call with row base R writes slot (R + (i>>3), i&7).
        #pragma unroll
        for (int t = 0; t < 2; ++t) {
            const int R  = wid * 16 + t * 8;           // uniform
            const int r  = R + (lane >> 3);
            const int cg = (lane & 7) ^ (r & 7);       // swizzled source chunk
            gl_lds16(Kbase + (size_t)(k0 + r) * DD + cg * 8, &Ks_l[R * 64]);
            gl_lds16(Vbase + (size_t)r * WW + k0 + cg * 8, &Vs_l[R * 64]);
        }
        __syncthreads();   // drains vmcnt(0): K/V (and first-iter Ml) visible

        // ---- fragments from LDS (conflict-free via swizzle) ----
        shortx8 kf[4][2], vf[4][2];
        #pragma unroll
        for (int jj = 0; jj < 4; ++jj) {
            const int r = 16 * jj + l15;
            #pragma unroll
            for (int hf = 0; hf < 2; ++hf)
                kf[jj][hf] = *(const shortx8*)&Ks_l[r * 64 + (((hf * 4 + quad) ^ (r & 7)) * 8)];
        }
        #pragma unroll
        for (int nn2 = 0; nn2 < 4; ++nn2) {
            const int r = 16 * nn2 + l15;
            #pragma unroll
            for (int hf = 0; hf < 2; ++hf)
                vf[nn2][hf] = *(const shortx8*)&Vs_l[r * 64 + (((hf * 4 + quad) ^ (r & 7)) * 8)];
        }
        float mv2[4];
        #pragma unroll
        for (int jj = 0; jj < 4; ++jj)
            mv2[jj] = Ml[k0 - ks0 + 16 * jj + l15];

        // ---- S = Q K^T ----
        floatx4 sacc[4];
        #pragma unroll
        for (int jj = 0; jj < 4; ++jj) {
            sacc[jj] = (floatx4)0.0f;
            sacc[jj] = __builtin_amdgcn_mfma_f32_16x16x32_bf16(qf[0], kf[jj][0], sacc[jj], 0, 0, 0);
            sacc[jj] = __builtin_amdgcn_mfma_f32_16x16x32_bf16(qf[1], kf[jj][1], sacc[jj], 0, 0, 0);
        }

        // ---- P = exp2(S * 0.125*log2e + (mask-8)*log2e) ----
        #pragma unroll
        for (int jj = 0; jj < 4; ++jj) {
            #pragma unroll
            for (int r = 0; r < 4; ++r) {
                float p = fast_exp2(fmaf(sacc[jj][r], C18, mv2[jj]));
                lst[r] += p;
                Pw[(quad * 4 + r) * PST + 16 * jj + l15] = f2bf(p);
            }
        }

        shortx8 pf0 = *(const shortx8*)&Pw[l15 * PST + quad * 8];
        shortx8 pf1 = *(const shortx8*)&Pw[l15 * PST + 32 + quad * 8];

        // ---- O += P V ----
        #pragma unroll
        for (int nn2 = 0; nn2 < 4; ++nn2) {
            oacc[nn2] = __builtin_amdgcn_mfma_f32_16x16x32_bf16(pf0, vf[nn2][0], oacc[nn2], 0, 0, 0);
            oacc[nn2] = __builtin_amdgcn_mfma_f32_16x16x32_bf16(pf1, vf[nn2][1], oacc[nn2], 0, 0, 0);
        }
        __syncthreads();   // all waves done reading K/V before next stage
    }

    // store raw partials: O (fp32, [nh][s][q][d]) and l ([nh][s][q])
    float* obase = Op + ((nh * KS + s) * WW + q0) * DD;
    #pragma unroll
    for (int nn2 = 0; nn2 < 4; ++nn2)
        #pragma unroll
        for (int r = 0; r < 4; ++r)
            obase[(size_t)(wid * 16 + quad * 4 + r) * DD + nn2 * 16 + l15] = oacc[nn2][r];

    #pragma unroll
    for (int r = 0; r < 4; ++r) lst[r] = rsum16(lst[r]);
    if (l15 == 0) {
        float* lbase = lp + (nh * KS + s) * WW + q0;
        #pragma unroll
        for (int r = 0; r < 4; ++r) lbase[wid * 16 + quad * 4 + r] = lst[r];
    }
}

// ---------------------------------------------------------------------------
// Reduce: sum KS partials, normalize, transpose to [N,C,W].
// grid (W/64, H, N), block 256.
// ---------------------------------------------------------------------------
#define RST 65

__global__ __launch_bounds__(256) void attn_reduce(
    const float* __restrict__ Op, const float* __restrict__ lp,
    float* __restrict__ out)
{
    __shared__ float Ol[64 * RST];   // [q][d], stride 65
    __shared__ float linv[64];

    const int q0 = blockIdx.x * 64;
    const int h  = blockIdx.y;
    const int n  = blockIdx.z;
    const int tid = threadIdx.x;
    const size_t nh = (size_t)n * HH + h;

    if (tid < 64) {
        float ls = 0.f;
        #pragma unroll
        for (int s = 0; s < KS; ++s) ls += lp[(nh * KS + s) * WW + q0 + tid];
        linv[tid] = 1.0f / ls;
    }
    __syncthreads();

    #pragma unroll
    for (int it = 0; it < 4; ++it) {
        const int idx = tid + it * 256;        // 64 q x 16 d-groups, dg fast
        const int q  = idx >> 4;
        const int d0 = (idx & 15) * 4;
        floatx4 a = (floatx4)0.0f;
        #pragma unroll
        for (int s = 0; s < KS; ++s)
            a += *(const floatx4*)&Op[(((nh * KS + s) * WW) + q0 + q) * DD + d0];
        a *= linv[q];
        #pragma unroll
        for (int i = 0; i < 4; ++i) Ol[q * RST + d0 + i] = a[i];
    }
    __syncthreads();

    float* obase = out + (nh * DD) * WW + q0;
    #pragma unroll
    for (int it = 0; it < 4; ++it) {
        const int idx = tid + it * 256;        // 64 d x 16 q-groups, qg fast
        const int q4 = (idx & 15) * 4;
        const int d  = idx >> 4;
        floatx4 v;
        #pragma unroll
        for (int i = 0; i < 4; ++i) v[i] = Ol[(q4 + i) * RST + d];
        *(floatx4*)&obase[(size_t)d * WW + q4] = v;
    }
}

// ---------------------------------------------------------------------------
extern "C" void kernel_launch(void* const* d_in, const int* in_sizes, int n_in,
                              void* d_out, int out_size, void* d_ws, size_t ws_size,
                              hipStream_t stream) {
    const float* x    = (const float*)d_in[0];
    const float* mask = (const float*)d_in[1];
    const float* wq   = (const float*)d_in[2];
    const float* bq   = (const float*)d_in[3];
    const float* wk   = (const float*)d_in[4];
    const float* bk   = (const float*)d_in[5];
    const float* wv   = (const float*)d_in[6];
    const float* bv   = (const float*)d_in[7];
    float* out = (float*)d_out;

    const size_t per = (size_t)NB * HH * WW * DD;   // 6,291,456
    short* Qb  = (short*)d_ws;
    short* Kb  = Qb + per;
    short* Vb  = Kb + per;
    // prep region (dead after qkv_gemm):
    short* XTh = Vb + per;
    short* XTl = XTh + per;
    short* Whp = XTl + per;
    short* Wlp = Whp + 3 * WSZ;
    // attention partials overlay the prep region:
    float* Op  = (float*)(Vb + per);                // KS*per fp32
    float* lp  = Op + (size_t)KS * per;             // KS*N*H*W fp32

    hipLaunchKernelGGL(prep_x, dim3(WW / 64, CC / 64, NB), dim3(256), 0, stream,
                       x, XTh, XTl);
    hipLaunchKernelGGL(prep_w, dim3((WSZ + 255) / 256), dim3(256), 0, stream,
                       wq, wk, wv, Whp, Wlp);
    hipLaunchKernelGGL(qkv_gemm, dim3(WW / 64, GG, 3 * NB), dim3(256), 0, stream,
                       XTh, XTl, Whp, Wlp, bq, bk, bv, Qb, Kb, Vb);
    hipLaunchKernelGGL(attn_split, dim3((WW / 64) * KS * HH * NB), dim3(256), 0, stream,
                       Qb, Kb, Vb, mask, Op, lp);
    hipLaunchKernelGGL(attn_reduce, dim3(WW / 64, HH, NB), dim3(256), 0, stream,
                       Op, lp, out);
}

// Round 9
// 229.814 us; speedup vs baseline: 2.3492x; 1.1412x over previous
//
#include <hip/hip_runtime.h>
#include <math.h>

typedef __attribute__((ext_vector_type(4))) float floatx4;
typedef __attribute__((ext_vector_type(8))) short shortx8;   // 8 bf16
typedef __attribute__((ext_vector_type(4))) short shortx4;   // 4 bf16 (8B)

#define NB 4
#define CC 768
#define WW 2048
#define HH 12
#define DD 64
#define GG 4
#define CG 192
#define HPG 3
#define L2E 1.4426950408889634f
#define C18 0.18033688011112043f   // 0.125 * log2(e)
#define MSH 11.541560327111707f    // 8.0 * log2(e)  (fixed softmax shift)

__device__ __forceinline__ float fast_exp2(float x) {
    return __builtin_amdgcn_exp2f(x);   // v_exp_f32 (log2 domain)
}

__device__ __forceinline__ short f2bf(float f) {
    union { float f; unsigned u; } v; v.f = f;
    unsigned r = v.u + 0x7fffu + ((v.u >> 16) & 1u);   // RNE
    return (short)(r >> 16);
}
__device__ __forceinline__ float bf2f(short h) {
    union { unsigned u; float f; } v;
    v.u = ((unsigned)(unsigned short)h) << 16;
    return v.f;
}

template<int CTRL>
__device__ __forceinline__ float dppror(float v) {
    return __int_as_float(__builtin_amdgcn_update_dpp(
        0, __float_as_int(v), CTRL, 0xf, 0xf, false));
}
__device__ __forceinline__ float rsum16(float v) {   // 16-lane DPP-row sum
    v += dppror<0x128>(v);
    v += dppror<0x124>(v);
    v += dppror<0x122>(v);
    v += dppror<0x121>(v);
    return v;
}

// async global->LDS, 16B per lane; lds base must be wave-uniform
__device__ __forceinline__ void gl_lds16(const void* g, void* l) {
    __builtin_amdgcn_global_load_lds(
        (const __attribute__((address_space(1))) unsigned int*)g,
        (__attribute__((address_space(3))) unsigned int*)l, 16, 0, 0);
}

// ---------------------------------------------------------------------------
// Prep 1: x [N,C,W] fp32 -> XTh/XTl [N,W,C] bf16 hi/lo (transpose + split).
// ---------------------------------------------------------------------------
__global__ __launch_bounds__(256) void prep_x(
    const float* __restrict__ x, short* __restrict__ XTh, short* __restrict__ XTl)
{
    const int w0 = blockIdx.x * 64;
    const int c0 = blockIdx.y * 64;
    const int n  = blockIdx.z;
    const int tid = threadIdx.x;
    const int w  = tid & 63;
    const int cb = c0 + (tid >> 6) * 16;

    float xv[16];
    #pragma unroll
    for (int j = 0; j < 16; ++j)
        xv[j] = x[((size_t)n * CC + cb + j) * WW + w0 + w];

    shortx8 hi0, hi1, lo0, lo1;
    #pragma unroll
    for (int j = 0; j < 8; ++j) {
        short h0 = f2bf(xv[j]);     hi0[j] = h0; lo0[j] = f2bf(xv[j]     - bf2f(h0));
        short h1 = f2bf(xv[j + 8]); hi1[j] = h1; lo1[j] = f2bf(xv[j + 8] - bf2f(h1));
    }
    const size_t ro = ((size_t)n * WW + w0 + w) * CC + cb;
    *(shortx8*)&XTh[ro]     = hi0;
    *(shortx8*)&XTh[ro + 8] = hi1;
    *(shortx8*)&XTl[ro]     = lo0;
    *(shortx8*)&XTl[ro + 8] = lo1;
}

// ---------------------------------------------------------------------------
// Prep 2: weights fp32 -> bf16 hi/lo, concat [mat][G,CG,CG].
// ---------------------------------------------------------------------------
#define WSZ (GG * CG * CG)   // 147456

__global__ __launch_bounds__(256) void prep_w(
    const float* __restrict__ wq, const float* __restrict__ wk,
    const float* __restrict__ wv, short* __restrict__ Wh, short* __restrict__ Wl)
{
    const int t = blockIdx.x * 256 + threadIdx.x;
    if (t >= WSZ) return;
    const float* src[3] = {wq, wk, wv};
    #pragma unroll
    for (int m = 0; m < 3; ++m) {
        float v = src[m][t];
        short h = f2bf(v);
        Wh[m * WSZ + t] = h;
        Wl[m * WSZ + t] = f2bf(v - bf2f(h));
    }
}

// ---------------------------------------------------------------------------
// Grouped 1x1 conv as bf16 hi/lo MFMA GEMM, one matrix (Q/K/V) per block.
// v2: X tile (64p x 192c, hi/lo) LDS-staged once per block via global_load_lds
// w=16 + XOR chunk swizzle (R8 technique); W loads stay global (few).
// XCD co-location: the 3 mat-blocks of one (n,g,p0) tile share an XCD.
// grid: 1536 1-D blocks, block 256.
// ---------------------------------------------------------------------------
__global__ __launch_bounds__(256) void qkv_gemm(
    const short* __restrict__ XTh, const short* __restrict__ XTl,
    const short* __restrict__ Wh, const short* __restrict__ Wl,
    const float* __restrict__ bq, const float* __restrict__ bk,
    const float* __restrict__ bv,
    short* __restrict__ Qb, short* __restrict__ Kb, short* __restrict__ Vb)
{
    __shared__ __align__(16) short Xh_l[64 * 192];   // 24 KB, [p][24 chunks] swz
    __shared__ __align__(16) short Xl_l[64 * 192];   // 24 KB

    // decode: tile = (n,g,p0) 0..511, mat 0..2; same tile -> same XCD
    const int lin  = blockIdx.x;
    const int xcd  = lin & 7;
    const int iw   = lin >> 3;              // 0..191
    const int mat  = iw % 3;
    const int tile = (iw / 3) * 8 + xcd;    // 0..511
    const int p0   = (tile & 31) * 64;
    const int g    = (tile >> 5) & 3;
    const int n    = tile >> 7;

    const int tid  = threadIdx.x;
    const int wid  = __builtin_amdgcn_readfirstlane(tid >> 6);
    const int lane = tid & 63;
    const int l15  = lane & 15;
    const int quad = lane >> 4;
    const int ob   = wid * 48;

    // ---- stage X tile: 1536 chunks of 16B (hi and lo), once per block ----
    // LDS slot (p, sc) holds global chunk (sc&~7)|((sc&7)^(p&7)).
    {
        const short* xhb = XTh + ((size_t)n * WW + p0) * CC + g * CG;
        const short* xlb = XTl + ((size_t)n * WW + p0) * CC + g * CG;
        #pragma unroll
        for (int rd = 0; rd < 6; ++rd) {
            const int Lb = rd * 256 + wid * 64;           // wave-uniform
            const int L  = Lb + lane;
            const int p  = (L * 2731) >> 16;              // L / 24
            const int sc = L - p * 24;
            const int ss = (sc & ~7) | ((sc & 7) ^ (p & 7));
            gl_lds16(xhb + (size_t)p * CC + ss * 8, &Xh_l[Lb * 8]);
            gl_lds16(xlb + (size_t)p * CC + ss * 8, &Xl_l[Lb * 8]);
        }
    }
    __syncthreads();

    const short* whm = Wh + (size_t)mat * WSZ + ((size_t)g * CG + ob + l15) * CG + quad * 8;
    const short* wlm = Wl + (size_t)mat * WSZ + ((size_t)g * CG + ob + l15) * CG + quad * 8;

    floatx4 acc[3][4];
    #pragma unroll
    for (int mi = 0; mi < 3; ++mi)
        #pragma unroll
        for (int ni = 0; ni < 4; ++ni) acc[mi][ni] = (floatx4)0.0f;

    #pragma unroll
    for (int ks = 0; ks < 6; ++ks) {
        shortx8 ah[3], al[3], bh[4], bl[4];
        #pragma unroll
        for (int mi = 0; mi < 3; ++mi) {
            ah[mi] = *(const shortx8*)(whm + (size_t)mi * 16 * CG + ks * 32);
            al[mi] = *(const shortx8*)(wlm + (size_t)mi * 16 * CG + ks * 32);
        }
        #pragma unroll
        for (int ni = 0; ni < 4; ++ni) {
            const int p  = ni * 16 + l15;
            const int vp = (ks >> 1) * 8 + ((((ks & 1) * 4) + quad) ^ (p & 7));
            const int off = (p * 24 + vp) * 8;
            bh[ni] = *(const shortx8*)&Xh_l[off];
            bl[ni] = *(const shortx8*)&Xl_l[off];
        }
        #pragma unroll
        for (int mi = 0; mi < 3; ++mi)
            #pragma unroll
            for (int ni = 0; ni < 4; ++ni) {
                acc[mi][ni] = __builtin_amdgcn_mfma_f32_16x16x32_bf16(ah[mi], bh[ni], acc[mi][ni], 0, 0, 0);
                acc[mi][ni] = __builtin_amdgcn_mfma_f32_16x16x32_bf16(ah[mi], bl[ni], acc[mi][ni], 0, 0, 0);
                acc[mi][ni] = __builtin_amdgcn_mfma_f32_16x16x32_bf16(al[mi], bh[ni], acc[mi][ni], 0, 0, 0);
            }
    }

    const float* bias = (mat == 0) ? bq : (mat == 1) ? bk : bv;
    short* Y = (mat == 0) ? Qb : (mat == 1) ? Kb : Vb;
    #pragma unroll
    for (int mi = 0; mi < 3; ++mi) {
        float4 b4 = *(const float4*)&bias[g * CG + ob + mi * 16 + quad * 4];
        const int o  = ob + mi * 16 + quad * 4;
        const int h  = g * HPG + (o >> 6);
        const int d0 = o & 63;
        const size_t nh = (size_t)n * HH + h;
        #pragma unroll
        for (int ni = 0; ni < 4; ++ni) {
            const int p = p0 + ni * 16 + l15;
            float y0 = acc[mi][ni][0] + b4.x;
            float y1 = acc[mi][ni][1] + b4.y;
            float y2 = acc[mi][ni][2] + b4.z;
            float y3 = acc[mi][ni][3] + b4.w;
            if (mat < 2) {
                shortx4 pk = { f2bf(y0), f2bf(y1), f2bf(y2), f2bf(y3) };
                *(shortx4*)&Y[(nh * WW + p) * DD + d0] = pk;   // [w][d]
            } else {
                const size_t vb = (nh * DD + d0) * WW + p;     // [d][w]
                Y[vb]          = f2bf(y0);
                Y[vb + WW]     = f2bf(y1);
                Y[vb + 2 * WW] = f2bf(y2);
                Y[vb + 3 * WW] = f2bf(y3);
            }
        }
    }
}

// ---------------------------------------------------------------------------
// Attention (full-K per block, LDS-staged, fused normalize+transpose output).
//  - K/V tiles staged once per block via global_load_lds w=16 + XOR swizzle
//  - fixed-shift softmax; per-row l accumulated in registers
//  - epilogue: normalize, LDS transpose (overlaid), coalesced [d][w] stores
// grid: 1536 1-D blocks (XCD swizzle: 6 (n,h) pairs per XCD), block 256.
// ---------------------------------------------------------------------------
#define PST 72
#define RST 65

__global__ __launch_bounds__(256) void attn_split(
    const short* __restrict__ Qb, const short* __restrict__ Kb,
    const short* __restrict__ Vb, const float* __restrict__ mask,
    float* __restrict__ out)
{
    __shared__ __align__(16) char smem[33792];
    short* Ks_l = (short*)smem;              // 8192 B [key][d] swizzled
    short* Vs_l = (short*)(smem + 8192);     // 8192 B [d][key] swizzled
    short* Pl   = (short*)(smem + 16384);    // 9216 B wave-private P strips
    float* Ml   = (float*)(smem + 25600);    // 8192 B pre-transformed mask

    const int lin  = blockIdx.x;
    const int xcd  = lin & 7;
    const int slot = lin >> 3;               // 0..191
    const int pair = xcd * 6 + (slot >> 5);  // 0..47
    const int qt   = slot & 31;
    const int n    = pair / HH;
    const int h    = pair % HH;
    const int q0   = qt * 64;

    const int tid  = threadIdx.x;
    const int wid  = __builtin_amdgcn_readfirstlane(tid >> 6);
    const int lane = tid & 63;
    const int l15  = lane & 15;
    const int quad = lane >> 4;

    const size_t nh = (size_t)n * HH + h;
    const short* Kbase = Kb + nh * WW * DD;   // [key][d]
    const short* Vbase = Vb + nh * DD * WW;   // [d][w]

    // stage pre-transformed mask (mask*log2e - 8*log2e) once
    {
        const float* mbase = mask + (size_t)n * WW;
        #pragma unroll
        for (int i = 0; i < WW / 256; ++i)
            Ml[tid + i * 256] = fmaf(mbase[tid + i * 256], L2E, -MSH);
    }

    shortx8 qf[2];
    {
        const short* qp = Qb + (nh * WW + q0 + wid * 16 + l15) * DD + quad * 8;
        qf[0] = *(const shortx8*)(qp);
        qf[1] = *(const shortx8*)(qp + 32);
    }

    floatx4 oacc[4];
    #pragma unroll
    for (int nn2 = 0; nn2 < 4; ++nn2) oacc[nn2] = (floatx4)0.0f;
    float lst[4] = {0.f, 0.f, 0.f, 0.f};

    short* Pw = Pl + wid * 16 * PST;

    for (int kt = 0; kt < WW / 64; ++kt) {
        const int k0 = kt * 64;

        // ---- stage K/V tile: wave wid covers rows [wid*16, wid*16+16) ----
        #pragma unroll
        for (int t = 0; t < 2; ++t) {
            const int R  = wid * 16 + t * 8;           // uniform
            const int r  = R + (lane >> 3);
            const int cg = (lane & 7) ^ (r & 7);       // swizzled source chunk
            gl_lds16(Kbase + (size_t)(k0 + r) * DD + cg * 8, &Ks_l[R * 64]);
            gl_lds16(Vbase + (size_t)r * WW + k0 + cg * 8, &Vs_l[R * 64]);
        }
        __syncthreads();   // drains vmcnt(0): K/V (and first-iter Ml) visible

        // ---- fragments from LDS (conflict-free via swizzle) ----
        shortx8 kf[4][2], vf[4][2];
        #pragma unroll
        for (int jj = 0; jj < 4; ++jj) {
            const int r = 16 * jj + l15;
            #pragma unroll
            for (int hf = 0; hf < 2; ++hf)
                kf[jj][hf] = *(const shortx8*)&Ks_l[r * 64 + (((hf * 4 + quad) ^ (r & 7)) * 8)];
        }
        #pragma unroll
        for (int nn2 = 0; nn2 < 4; ++nn2) {
            const int r = 16 * nn2 + l15;
            #pragma unroll
            for (int hf = 0; hf < 2; ++hf)
                vf[nn2][hf] = *(const shortx8*)&Vs_l[r * 64 + (((hf * 4 + quad) ^ (r & 7)) * 8)];
        }
        float mv2[4];
        #pragma unroll
        for (int jj = 0; jj < 4; ++jj)
            mv2[jj] = Ml[k0 + 16 * jj + l15];

        // ---- S = Q K^T ----
        floatx4 sacc[4];
        #pragma unroll
        for (int jj = 0; jj < 4; ++jj) {
            sacc[jj] = (floatx4)0.0f;
            sacc[jj] = __builtin_amdgcn_mfma_f32_16x16x32_bf16(qf[0], kf[jj][0], sacc[jj], 0, 0, 0);
            sacc[jj] = __builtin_amdgcn_mfma_f32_16x16x32_bf16(qf[1], kf[jj][1], sacc[jj], 0, 0, 0);
        }

        // ---- P = exp2(S * 0.125*log2e + (mask-8)*log2e) ----
        #pragma unroll
        for (int jj = 0; jj < 4; ++jj) {
            #pragma unroll
            for (int r = 0; r < 4; ++r) {
                float p = fast_exp2(fmaf(sacc[jj][r], C18, mv2[jj]));
                lst[r] += p;
                Pw[(quad * 4 + r) * PST + 16 * jj + l15] = f2bf(p);
            }
        }

        shortx8 pf0 = *(const shortx8*)&Pw[l15 * PST + quad * 8];
        shortx8 pf1 = *(const shortx8*)&Pw[l15 * PST + 32 + quad * 8];

        // ---- O += P V ----
        #pragma unroll
        for (int nn2 = 0; nn2 < 4; ++nn2) {
            oacc[nn2] = __builtin_amdgcn_mfma_f32_16x16x32_bf16(pf0, vf[nn2][0], oacc[nn2], 0, 0, 0);
            oacc[nn2] = __builtin_amdgcn_mfma_f32_16x16x32_bf16(pf1, vf[nn2][1], oacc[nn2], 0, 0, 0);
        }
        __syncthreads();   // all waves done reading K/V before next stage
    }

    // ---- epilogue: normalize, transpose via LDS (overlay), store [d][w] ----
    float linv[4];
    #pragma unroll
    for (int r = 0; r < 4; ++r) linv[r] = 1.0f / rsum16(lst[r]);

    float* Ol = (float*)smem;   // 16640 B, overlays Ks/Vs/Pl-head (dead now)
    #pragma unroll
    for (int nn2 = 0; nn2 < 4; ++nn2)
        #pragma unroll
        for (int r = 0; r < 4; ++r)
            Ol[(wid * 16 + quad * 4 + r) * RST + nn2 * 16 + l15] = oacc[nn2][r] * linv[r];
    __syncthreads();

    float* obase = out + (nh * DD) * WW + q0;
    #pragma unroll
    for (int it = 0; it < 4; ++it) {
        const int idx = tid + it * 256;        // 64 d x 16 q-groups
        const int q4 = (idx & 15) * 4;
        const int d  = idx >> 4;
        floatx4 v;
        #pragma unroll
        for (int i = 0; i < 4; ++i) v[i] = Ol[(q4 + i) * RST + d];
        *(floatx4*)&obase[(size_t)d * WW + q4] = v;
    }
}

// ---------------------------------------------------------------------------
extern "C" void kernel_launch(void* const* d_in, const int* in_sizes, int n_in,
                              void* d_out, int out_size, void* d_ws, size_t ws_size,
                              hipStream_t stream) {
    const float* x    = (const float*)d_in[0];
    const float* mask = (const float*)d_in[1];
    const float* wq   = (const float*)d_in[2];
    const float* bq   = (const float*)d_in[3];
    const float* wk   = (const float*)d_in[4];
    const float* bk   = (const float*)d_in[5];
    const float* wv   = (const float*)d_in[6];
    const float* bv   = (const float*)d_in[7];
    float* out = (float*)d_out;

    const size_t per = (size_t)NB * HH * WW * DD;   // 6,291,456
    short* Qb  = (short*)d_ws;
    short* Kb  = Qb + per;
    short* Vb  = Kb + per;
    short* XTh = Vb + per;
    short* XTl = XTh + per;
    short* Whp = XTl + per;
    short* Wlp = Whp + 3 * WSZ;

    hipLaunchKernelGGL(prep_x, dim3(WW / 64, CC / 64, NB), dim3(256), 0, stream,
                       x, XTh, XTl);
    hipLaunchKernelGGL(prep_w, dim3((WSZ + 255) / 256), dim3(256), 0, stream,
                       wq, wk, wv, Whp, Wlp);
    hipLaunchKernelGGL(qkv_gemm, dim3(1536), dim3(256), 0, stream,
                       XTh, XTl, Whp, Wlp, bq, bk, bv, Qb, Kb, Vb);
    hipLaunchKernelGGL(attn_split, dim3(1536), dim3(256), 0, stream,
                       Qb, Kb, Vb, mask, out);
}

// Round 10
// 224.862 us; speedup vs baseline: 2.4009x; 1.0220x over previous
//
#include <hip/hip_runtime.h>
#include <math.h>

typedef __attribute__((ext_vector_type(4))) float floatx4;
typedef __attribute__((ext_vector_type(8))) short shortx8;   // 8 bf16
typedef __attribute__((ext_vector_type(4))) short shortx4;   // 4 bf16 (8B)

#define NB 4
#define CC 768
#define WW 2048
#define HH 12
#define DD 64
#define GG 4
#define CG 192
#define HPG 3
#define L2E 1.4426950408889634f
#define C18 0.18033688011112043f   // 0.125 * log2(e)
#define MSH 11.541560327111707f    // 8.0 * log2(e)  (fixed softmax shift)

__device__ __forceinline__ float fast_exp2(float x) {
    return __builtin_amdgcn_exp2f(x);   // v_exp_f32 (log2 domain)
}

__device__ __forceinline__ short f2bf(float f) {
    union { float f; unsigned u; } v; v.f = f;
    unsigned r = v.u + 0x7fffu + ((v.u >> 16) & 1u);   // RNE
    return (short)(r >> 16);
}
__device__ __forceinline__ float bf2f(short h) {
    union { unsigned u; float f; } v;
    v.u = ((unsigned)(unsigned short)h) << 16;
    return v.f;
}

template<int CTRL>
__device__ __forceinline__ float dppror(float v) {
    return __int_as_float(__builtin_amdgcn_update_dpp(
        0, __float_as_int(v), CTRL, 0xf, 0xf, false));
}
__device__ __forceinline__ float rsum16(float v) {   // 16-lane DPP-row sum
    v += dppror<0x128>(v);
    v += dppror<0x124>(v);
    v += dppror<0x122>(v);
    v += dppror<0x121>(v);
    return v;
}

// async global->LDS, 16B per lane; lds base must be wave-uniform
__device__ __forceinline__ void gl_lds16(const void* g, void* l) {
    __builtin_amdgcn_global_load_lds(
        (const __attribute__((address_space(1))) unsigned int*)g,
        (__attribute__((address_space(3))) unsigned int*)l, 16, 0, 0);
}

// ---------------------------------------------------------------------------
// Prep 1: x [N,C,W] fp32 -> XTh/XTl [N,W,C] bf16 hi/lo (transpose + split).
// v2: LDS transpose so global writes are coalesced shortx8 rows
// (R9 wrote 16B per lane at 1536B stride = 64 lines/instr + RMW).
// ---------------------------------------------------------------------------
__global__ __launch_bounds__(256) void prep_x(
    const float* __restrict__ x, short* __restrict__ XTh, short* __restrict__ XTl)
{
    __shared__ short Th[64 * 72];   // [w][c64+pad8]
    __shared__ short Tl[64 * 72];

    const int w0 = blockIdx.x * 64;
    const int c0 = blockIdx.y * 64;
    const int n  = blockIdx.z;
    const int tid = threadIdx.x;
    const int w  = tid & 63;
    const int cb = (tid >> 6) * 16;      // c-local base

    float xv[16];
    #pragma unroll
    for (int j = 0; j < 16; ++j)
        xv[j] = x[((size_t)n * CC + c0 + cb + j) * WW + w0 + w];

    shortx8 hi0, hi1, lo0, lo1;
    #pragma unroll
    for (int j = 0; j < 8; ++j) {
        short h0 = f2bf(xv[j]);     hi0[j] = h0; lo0[j] = f2bf(xv[j]     - bf2f(h0));
        short h1 = f2bf(xv[j + 8]); hi1[j] = h1; lo1[j] = f2bf(xv[j + 8] - bf2f(h1));
    }
    *(shortx8*)&Th[w * 72 + cb]     = hi0;
    *(shortx8*)&Th[w * 72 + cb + 8] = hi1;
    *(shortx8*)&Tl[w * 72 + cb]     = lo0;
    *(shortx8*)&Tl[w * 72 + cb + 8] = lo1;
    __syncthreads();

    // coalesced writes: (wr, cc) -> 1KB-contiguous across the wave
    const int wr = tid >> 2;
    const int cc = (tid & 3) * 16;
    const size_t ro = ((size_t)n * WW + w0 + wr) * CC + c0 + cc;
    *(shortx8*)&XTh[ro]     = *(const shortx8*)&Th[wr * 72 + cc];
    *(shortx8*)&XTh[ro + 8] = *(const shortx8*)&Th[wr * 72 + cc + 8];
    *(shortx8*)&XTl[ro]     = *(const shortx8*)&Tl[wr * 72 + cc];
    *(shortx8*)&XTl[ro + 8] = *(const shortx8*)&Tl[wr * 72 + cc + 8];
}

// ---------------------------------------------------------------------------
// Prep 2: weights fp32 -> bf16 hi/lo, concat [mat][G,CG,CG].
// ---------------------------------------------------------------------------
#define WSZ (GG * CG * CG)   // 147456

__global__ __launch_bounds__(256) void prep_w(
    const float* __restrict__ wq, const float* __restrict__ wk,
    const float* __restrict__ wv, short* __restrict__ Wh, short* __restrict__ Wl)
{
    const int t = blockIdx.x * 256 + threadIdx.x;
    if (t >= WSZ) return;
    const float* src[3] = {wq, wk, wv};
    #pragma unroll
    for (int m = 0; m < 3; ++m) {
        float v = src[m][t];
        short h = f2bf(v);
        Wh[m * WSZ + t] = h;
        Wl[m * WSZ + t] = f2bf(v - bf2f(h));
    }
}

// ---------------------------------------------------------------------------
// Grouped 1x1 conv as bf16 hi/lo MFMA GEMM, one matrix (Q/K/V) per block.
// v3: epilogue LDS-transposes results so ALL global stores are coalesced
// contiguous shortx8 rows (R9: Q/K = 8B/lane @128B stride = 64 lines/instr).
// grid: 1536 1-D blocks, block 256.
// ---------------------------------------------------------------------------
__global__ __launch_bounds__(256) void qkv_gemm(
    const short* __restrict__ XTh, const short* __restrict__ XTl,
    const short* __restrict__ Wh, const short* __restrict__ Wl,
    const float* __restrict__ bq, const float* __restrict__ bk,
    const float* __restrict__ bv,
    short* __restrict__ Qb, short* __restrict__ Kb, short* __restrict__ Vb)
{
    __shared__ __align__(16) char smem[49152];
    short* Xh_l = (short*)smem;              // 24 KB, [p][24 chunks] swz
    short* Xl_l = (short*)(smem + 24576);    // 24 KB

    // decode: tile = (n,g,p0) 0..511, mat 0..2; same tile -> same XCD
    const int lin  = blockIdx.x;
    const int xcd  = lin & 7;
    const int iw   = lin >> 3;              // 0..191
    const int mat  = iw % 3;
    const int tile = (iw / 3) * 8 + xcd;    // 0..511
    const int p0   = (tile & 31) * 64;
    const int g    = (tile >> 5) & 3;
    const int n    = tile >> 7;

    const int tid  = threadIdx.x;
    const int wid  = __builtin_amdgcn_readfirstlane(tid >> 6);
    const int lane = tid & 63;
    const int l15  = lane & 15;
    const int quad = lane >> 4;
    const int ob   = wid * 48;

    // ---- stage X tile: 1536 chunks of 16B (hi and lo), once per block ----
    {
        const short* xhb = XTh + ((size_t)n * WW + p0) * CC + g * CG;
        const short* xlb = XTl + ((size_t)n * WW + p0) * CC + g * CG;
        #pragma unroll
        for (int rd = 0; rd < 6; ++rd) {
            const int Lb = rd * 256 + wid * 64;           // wave-uniform
            const int L  = Lb + lane;
            const int p  = (L * 2731) >> 16;              // L / 24
            const int sc = L - p * 24;
            const int ss = (sc & ~7) | ((sc & 7) ^ (p & 7));
            gl_lds16(xhb + (size_t)p * CC + ss * 8, &Xh_l[Lb * 8]);
            gl_lds16(xlb + (size_t)p * CC + ss * 8, &Xl_l[Lb * 8]);
        }
    }
    __syncthreads();

    const short* whm = Wh + (size_t)mat * WSZ + ((size_t)g * CG + ob + l15) * CG + quad * 8;
    const short* wlm = Wl + (size_t)mat * WSZ + ((size_t)g * CG + ob + l15) * CG + quad * 8;

    floatx4 acc[3][4];
    #pragma unroll
    for (int mi = 0; mi < 3; ++mi)
        #pragma unroll
        for (int ni = 0; ni < 4; ++ni) acc[mi][ni] = (floatx4)0.0f;

    #pragma unroll
    for (int ks = 0; ks < 6; ++ks) {
        shortx8 ah[3], al[3], bh[4], bl[4];
        #pragma unroll
        for (int mi = 0; mi < 3; ++mi) {
            ah[mi] = *(const shortx8*)(whm + (size_t)mi * 16 * CG + ks * 32);
            al[mi] = *(const shortx8*)(wlm + (size_t)mi * 16 * CG + ks * 32);
        }
        #pragma unroll
        for (int ni = 0; ni < 4; ++ni) {
            const int p  = ni * 16 + l15;
            const int vp = (ks >> 1) * 8 + ((((ks & 1) * 4) + quad) ^ (p & 7));
            const int off = (p * 24 + vp) * 8;
            bh[ni] = *(const shortx8*)&Xh_l[off];
            bl[ni] = *(const shortx8*)&Xl_l[off];
        }
        #pragma unroll
        for (int mi = 0; mi < 3; ++mi)
            #pragma unroll
            for (int ni = 0; ni < 4; ++ni) {
                acc[mi][ni] = __builtin_amdgcn_mfma_f32_16x16x32_bf16(ah[mi], bh[ni], acc[mi][ni], 0, 0, 0);
                acc[mi][ni] = __builtin_amdgcn_mfma_f32_16x16x32_bf16(ah[mi], bl[ni], acc[mi][ni], 0, 0, 0);
                acc[mi][ni] = __builtin_amdgcn_mfma_f32_16x16x32_bf16(al[mi], bh[ni], acc[mi][ni], 0, 0, 0);
            }
    }

    const float* bias = (mat == 0) ? bq : (mat == 1) ? bk : bv;
    short* Y = (mat == 0) ? Qb : (mat == 1) ? Kb : Vb;

    __syncthreads();   // all frag reads of Xh_l/Xl_l done before overlay

    if (mat < 2) {
        // ---- Q/K: LDS [p][o stride 200], then coalesced [w][d] rows ----
        short* T = (short*)smem;   // 64*200*2 = 25600 B
        #pragma unroll
        for (int mi = 0; mi < 3; ++mi) {
            float4 b4 = *(const float4*)&bias[g * CG + ob + mi * 16 + quad * 4];
            const int o = ob + mi * 16 + quad * 4;
            #pragma unroll
            for (int ni = 0; ni < 4; ++ni) {
                const int p = ni * 16 + l15;
                T[p * 200 + o]     = f2bf(acc[mi][ni][0] + b4.x);
                T[p * 200 + o + 1] = f2bf(acc[mi][ni][1] + b4.y);
                T[p * 200 + o + 2] = f2bf(acc[mi][ni][2] + b4.z);
                T[p * 200 + o + 3] = f2bf(acc[mi][ni][3] + b4.w);
            }
        }
        __syncthreads();
        #pragma unroll
        for (int hc = 0; hc < HPG; ++hc) {
            const size_t nh = (size_t)n * HH + g * HPG + hc;
            #pragma unroll
            for (int half = 0; half < 2; ++half) {
                const int idx = tid + half * 256;
                const int p  = idx >> 3;
                const int dc = (idx & 7) * 8;
                *(shortx8*)&Y[(nh * WW + p0 + p) * DD + dc] =
                    *(const shortx8*)&T[p * 200 + hc * 64 + dc];
            }
        }
    } else {
        // ---- V: LDS [o][p stride 68], then coalesced [d][w] rows ----
        short* T = (short*)smem;   // 192*68*2 = 26112 B
        #pragma unroll
        for (int mi = 0; mi < 3; ++mi) {
            float4 b4 = *(const float4*)&bias[g * CG + ob + mi * 16 + quad * 4];
            const int o = ob + mi * 16 + quad * 4;
            #pragma unroll
            for (int ni = 0; ni < 4; ++ni) {
                const int p = ni * 16 + l15;
                T[(o)     * 68 + p] = f2bf(acc[mi][ni][0] + b4.x);
                T[(o + 1) * 68 + p] = f2bf(acc[mi][ni][1] + b4.y);
                T[(o + 2) * 68 + p] = f2bf(acc[mi][ni][2] + b4.z);
                T[(o + 3) * 68 + p] = f2bf(acc[mi][ni][3] + b4.w);
            }
        }
        __syncthreads();
        #pragma unroll
        for (int pass = 0; pass < 6; ++pass) {
            const int idx = tid + pass * 256;
            const int o  = idx >> 3;
            const int pc = (idx & 7) * 8;
            const size_t nh = (size_t)n * HH + g * HPG + (o >> 6);
            const int d = o & 63;
            *(shortx8*)&Y[(nh * DD + d) * WW + p0 + pc] =
                *(const shortx8*)&T[o * 68 + pc];
        }
    }
}

// ---------------------------------------------------------------------------
// Attention (unchanged from R9: full-K, LDS-staged, fused epilogue).
// grid: 1536 1-D blocks (XCD swizzle: 6 (n,h) pairs per XCD), block 256.
// ---------------------------------------------------------------------------
#define PST 72
#define RST 65

__global__ __launch_bounds__(256) void attn_split(
    const short* __restrict__ Qb, const short* __restrict__ Kb,
    const short* __restrict__ Vb, const float* __restrict__ mask,
    float* __restrict__ out)
{
    __shared__ __align__(16) char smem[33792];
    short* Ks_l = (short*)smem;              // 8192 B [key][d] swizzled
    short* Vs_l = (short*)(smem + 8192);     // 8192 B [d][key] swizzled
    short* Pl   = (short*)(smem + 16384);    // 9216 B wave-private P strips
    float* Ml   = (float*)(smem + 25600);    // 8192 B pre-transformed mask

    const int lin  = blockIdx.x;
    const int xcd  = lin & 7;
    const int slot = lin >> 3;               // 0..191
    const int pair = xcd * 6 + (slot >> 5);  // 0..47
    const int qt   = slot & 31;
    const int n    = pair / HH;
    const int h    = pair % HH;
    const int q0   = qt * 64;

    const int tid  = threadIdx.x;
    const int wid  = __builtin_amdgcn_readfirstlane(tid >> 6);
    const int lane = tid & 63;
    const int l15  = lane & 15;
    const int quad = lane >> 4;

    const size_t nh = (size_t)n * HH + h;
    const short* Kbase = Kb + nh * WW * DD;   // [key][d]
    const short* Vbase = Vb + nh * DD * WW;   // [d][w]

    {
        const float* mbase = mask + (size_t)n * WW;
        #pragma unroll
        for (int i = 0; i < WW / 256; ++i)
            Ml[tid + i * 256] = fmaf(mbase[tid + i * 256], L2E, -MSH);
    }

    shortx8 qf[2];
    {
        const short* qp = Qb + (nh * WW + q0 + wid * 16 + l15) * DD + quad * 8;
        qf[0] = *(const shortx8*)(qp);
        qf[1] = *(const shortx8*)(qp + 32);
    }

    floatx4 oacc[4];
    #pragma unroll
    for (int nn2 = 0; nn2 < 4; ++nn2) oacc[nn2] = (floatx4)0.0f;
    float lst[4] = {0.f, 0.f, 0.f, 0.f};

    short* Pw = Pl + wid * 16 * PST;

    for (int kt = 0; kt < WW / 64; ++kt) {
        const int k0 = kt * 64;

        #pragma unroll
        for (int t = 0; t < 2; ++t) {
            const int R  = wid * 16 + t * 8;           // uniform
            const int r  = R + (lane >> 3);
            const int cg = (lane & 7) ^ (r & 7);       // swizzled source chunk
            gl_lds16(Kbase + (size_t)(k0 + r) * DD + cg * 8, &Ks_l[R * 64]);
            gl_lds16(Vbase + (size_t)r * WW + k0 + cg * 8, &Vs_l[R * 64]);
        }
        __syncthreads();

        shortx8 kf[4][2], vf[4][2];
        #pragma unroll
        for (int jj = 0; jj < 4; ++jj) {
            const int r = 16 * jj + l15;
            #pragma unroll
            for (int hf = 0; hf < 2; ++hf)
                kf[jj][hf] = *(const shortx8*)&Ks_l[r * 64 + (((hf * 4 + quad) ^ (r & 7)) * 8)];
        }
        #pragma unroll
        for (int nn2 = 0; nn2 < 4; ++nn2) {
            const int r = 16 * nn2 + l15;
            #pragma unroll
            for (int hf = 0; hf < 2; ++hf)
                vf[nn2][hf] = *(const shortx8*)&Vs_l[r * 64 + (((hf * 4 + quad) ^ (r & 7)) * 8)];
        }
        float mv2[4];
        #pragma unroll
        for (int jj = 0; jj < 4; ++jj)
            mv2[jj] = Ml[k0 + 16 * jj + l15];

        floatx4 sacc[4];
        #pragma unroll
        for (int jj = 0; jj < 4; ++jj) {
            sacc[jj] = (floatx4)0.0f;
            sacc[jj] = __builtin_amdgcn_mfma_f32_16x16x32_bf16(qf[0], kf[jj][0], sacc[jj], 0, 0, 0);
            sacc[jj] = __builtin_amdgcn_mfma_f32_16x16x32_bf16(qf[1], kf[jj][1], sacc[jj], 0, 0, 0);
        }

        #pragma unroll
        for (int jj = 0; jj < 4; ++jj) {
            #pragma unroll
            for (int r = 0; r < 4; ++r) {
                float p = fast_exp2(fmaf(sacc[jj][r], C18, mv2[jj]));
                lst[r] += p;
                Pw[(quad * 4 + r) * PST + 16 * jj + l15] = f2bf(p);
            }
        }

        shortx8 pf0 = *(const shortx8*)&Pw[l15 * PST + quad * 8];
        shortx8 pf1 = *(const shortx8*)&Pw[l15 * PST + 32 + quad * 8];

        #pragma unroll
        for (int nn2 = 0; nn2 < 4; ++nn2) {
            oacc[nn2] = __builtin_amdgcn_mfma_f32_16x16x32_bf16(pf0, vf[nn2][0], oacc[nn2], 0, 0, 0);
            oacc[nn2] = __builtin_amdgcn_mfma_f32_16x16x32_bf16(pf1, vf[nn2][1], oacc[nn2], 0, 0, 0);
        }
        __syncthreads();
    }

    float linv[4];
    #pragma unroll
    for (int r = 0; r < 4; ++r) linv[r] = 1.0f / rsum16(lst[r]);

    float* Ol = (float*)smem;
    #pragma unroll
    for (int nn2 = 0; nn2 < 4; ++nn2)
        #pragma unroll
        for (int r = 0; r < 4; ++r)
            Ol[(wid * 16 + quad * 4 + r) * RST + nn2 * 16 + l15] = oacc[nn2][r] * linv[r];
    __syncthreads();

    float* obase = out + (nh * DD) * WW + q0;
    #pragma unroll
    for (int it = 0; it < 4; ++it) {
        const int idx = tid + it * 256;
        const int q4 = (idx & 15) * 4;
        const int d  = idx >> 4;
        floatx4 v;
        #pragma unroll
        for (int i = 0; i < 4; ++i) v[i] = Ol[(q4 + i) * RST + d];
        *(floatx4*)&obase[(size_t)d * WW + q4] = v;
    }
}

// ---------------------------------------------------------------------------
extern "C" void kernel_launch(void* const* d_in, const int* in_sizes, int n_in,
                              void* d_out, int out_size, void* d_ws, size_t ws_size,
                              hipStream_t stream) {
    const float* x    = (const float*)d_in[0];
    const float* mask = (const float*)d_in[1];
    const float* wq   = (const float*)d_in[2];
    const float* bq   = (const float*)d_in[3];
    const float* wk   = (const float*)d_in[4];
    const float* bk   = (const float*)d_in[5];
    const float* wv   = (const float*)d_in[6];
    const float* bv   = (const float*)d_in[7];
    float* out = (float*)d_out;

    const size_t per = (size_t)NB * HH * WW * DD;   // 6,291,456
    short* Qb  = (short*)d_ws;
    short* Kb  = Qb + per;
    short* Vb  = Kb + per;
    short* XTh = Vb + per;
    short* XTl = XTh + per;
    short* Whp = XTl + per;
    short* Wlp = Whp + 3 * WSZ;

    hipLaunchKernelGGL(prep_x, dim3(WW / 64, CC / 64, NB), dim3(256), 0, stream,
                       x, XTh, XTl);
    hipLaunchKernelGGL(prep_w, dim3((WSZ + 255) / 256), dim3(256), 0, stream,
                       wq, wk, wv, Whp, Wlp);
    hipLaunchKernelGGL(qkv_gemm, dim3(1536), dim3(256), 0, stream,
                       XTh, XTl, Whp, Wlp, bq, bk, bv, Qb, Kb, Vb);
    hipLaunchKernelGGL(attn_split, dim3(1536), dim3(256), 0, stream,
                       Qb, Kb, Vb, mask, out);
}

// Round 11
// 199.542 us; speedup vs baseline: 2.7056x; 1.1269x over previous
//
#include <hip/hip_runtime.h>
#include <math.h>

typedef __attribute__((ext_vector_type(4))) float floatx4;
typedef __attribute__((ext_vector_type(8))) short shortx8;   // 8 bf16
typedef __attribute__((ext_vector_type(4))) short shortx4;   // 4 bf16 (8B)

#define NB 4
#define CC 768
#define WW 2048
#define HH 12
#define DD 64
#define GG 4
#define CG 192
#define HPG 3
#define L2E 1.4426950408889634f
#define C18 0.18033688011112043f   // 0.125 * log2(e)
#define MSH 11.541560327111707f    // 8.0 * log2(e)  (fixed softmax shift)
#define WSZ (GG * CG * CG)         // 147456

__device__ __forceinline__ float fast_exp2(float x) {
    return __builtin_amdgcn_exp2f(x);   // v_exp_f32 (log2 domain)
}

__device__ __forceinline__ short f2bf(float f) {
    union { float f; unsigned u; } v; v.f = f;
    unsigned r = v.u + 0x7fffu + ((v.u >> 16) & 1u);   // RNE
    return (short)(r >> 16);
}

template<int CTRL>
__device__ __forceinline__ float dppror(float v) {
    return __int_as_float(__builtin_amdgcn_update_dpp(
        0, __float_as_int(v), CTRL, 0xf, 0xf, false));
}
__device__ __forceinline__ float rsum16(float v) {   // 16-lane DPP-row sum
    v += dppror<0x128>(v);
    v += dppror<0x124>(v);
    v += dppror<0x122>(v);
    v += dppror<0x121>(v);
    return v;
}

// async global->LDS, 16B per lane; lds base must be wave-uniform
__device__ __forceinline__ void gl_lds16(const void* g, void* l) {
    __builtin_amdgcn_global_load_lds(
        (const __attribute__((address_space(1))) unsigned int*)g,
        (__attribute__((address_space(3))) unsigned int*)l, 16, 0, 0);
}

// ---------------------------------------------------------------------------
// Prep (merged): blocks [0,1536): x -> XTh [N,W,C] bf16 (LDS-transposed,
// coalesced both ways). blocks [1536,2112): weights -> Wf fragment-major:
// Wf[m][((g*12+ob16)*6+ks)*512 + quadk*128 + o15*8 + j]  so a GEMM A-frag is
// a wave-uniform base + lane*16B contiguous load (no 16-line gathers).
// ---------------------------------------------------------------------------
__global__ __launch_bounds__(256) void prep(
    const float* __restrict__ x,
    const float* __restrict__ wq, const float* __restrict__ wk,
    const float* __restrict__ wv,
    short* __restrict__ XTh, short* __restrict__ Wf)
{
    __shared__ short Th[64 * 72];
    const int tid = threadIdx.x;
    const int b   = blockIdx.x;

    if (b < 1536) {
        const int w0 = (b & 31) * 64;
        const int c0 = ((b >> 5) % 12) * 64;
        const int n  = b / 384;
        const int w  = tid & 63;
        const int cb = (tid >> 6) * 16;

        float xv[16];
        #pragma unroll
        for (int j = 0; j < 16; ++j)
            xv[j] = x[((size_t)n * CC + c0 + cb + j) * WW + w0 + w];

        shortx8 hi0, hi1;
        #pragma unroll
        for (int j = 0; j < 8; ++j) { hi0[j] = f2bf(xv[j]); hi1[j] = f2bf(xv[j + 8]); }
        *(shortx8*)&Th[w * 72 + cb]     = hi0;
        *(shortx8*)&Th[w * 72 + cb + 8] = hi1;
        __syncthreads();

        const int wr = tid >> 2;
        const int cc = (tid & 3) * 16;
        const size_t ro = ((size_t)n * WW + w0 + wr) * CC + c0 + cc;
        *(shortx8*)&XTh[ro]     = *(const shortx8*)&Th[wr * 72 + cc];
        *(shortx8*)&XTh[ro + 8] = *(const shortx8*)&Th[wr * 72 + cc + 8];
    } else {
        const int t = (b - 1536) * 256 + tid;          // < WSZ
        const int g  = t / (CG * CG);
        const int r  = t - g * (CG * CG);
        const int o  = r / CG;
        const int k  = r - o * CG;
        const int off = (((g * 12 + (o >> 4)) * 6 + (k >> 5)) * 512)
                      + ((k >> 3) & 3) * 128 + (o & 15) * 8 + (k & 7);
        const float* src[3] = {wq, wk, wv};
        #pragma unroll
        for (int m = 0; m < 3; ++m)
            Wf[m * WSZ + off] = f2bf(src[m][t]);
    }
}

// ---------------------------------------------------------------------------
// Grouped 1x1 conv as single-bf16 MFMA GEMM, one matrix (Q/K/V) per block.
// v4: single precision pass (12 MFMA/ks-wave), fragment-major W (coalesced
// frag loads), X tile LDS-staged via global_load_lds + XOR swizzle.
// grid: 1536 1-D blocks, block 256.  LDS 25.5 KB -> 6 blocks/CU.
// ---------------------------------------------------------------------------
__global__ __launch_bounds__(256) void qkv_gemm(
    const short* __restrict__ XTh, const short* __restrict__ Wf,
    const float* __restrict__ bq, const float* __restrict__ bk,
    const float* __restrict__ bv,
    short* __restrict__ Qb, short* __restrict__ Kb, short* __restrict__ Vb)
{
    __shared__ __align__(16) char smem[26112];
    short* Xh_l = (short*)smem;              // 24576 B, [p][24 chunks] swz

    // decode: tile = (n,g,p0) 0..511, mat 0..2; same tile -> same XCD
    const int lin  = blockIdx.x;
    const int xcd  = lin & 7;
    const int iw   = lin >> 3;              // 0..191
    const int mat  = iw % 3;
    const int tile = (iw / 3) * 8 + xcd;    // 0..511
    const int p0   = (tile & 31) * 64;
    const int g    = (tile >> 5) & 3;
    const int n    = tile >> 7;

    const int tid  = threadIdx.x;
    const int wid  = __builtin_amdgcn_readfirstlane(tid >> 6);
    const int lane = tid & 63;
    const int l15  = lane & 15;
    const int quad = lane >> 4;
    const int ob   = wid * 48;

    // ---- stage X tile: 1536 chunks of 16B, once per block ----
    {
        const short* xhb = XTh + ((size_t)n * WW + p0) * CC + g * CG;
        #pragma unroll
        for (int rd = 0; rd < 6; ++rd) {
            const int Lb = rd * 256 + wid * 64;           // wave-uniform
            const int L  = Lb + lane;
            const int p  = (L * 2731) >> 16;              // L / 24
            const int sc = L - p * 24;
            const int ss = (sc & ~7) | ((sc & 7) ^ (p & 7));
            gl_lds16(xhb + (size_t)p * CC + ss * 8, &Xh_l[Lb * 8]);
        }
    }
    __syncthreads();

    floatx4 acc[3][4];
    #pragma unroll
    for (int mi = 0; mi < 3; ++mi)
        #pragma unroll
        for (int ni = 0; ni < 4; ++ni) acc[mi][ni] = (floatx4)0.0f;

    const short* wfm = Wf + (size_t)mat * WSZ + lane * 8;

    #pragma unroll
    for (int ks = 0; ks < 6; ++ks) {
        shortx8 ah[3], bh[4];
        #pragma unroll
        for (int mi = 0; mi < 3; ++mi)
            ah[mi] = *(const shortx8*)(wfm + (((g * 12 + wid * 3 + mi) * 6 + ks) << 9));
        #pragma unroll
        for (int ni = 0; ni < 4; ++ni) {
            const int p  = ni * 16 + l15;
            const int vp = (ks >> 1) * 8 + ((((ks & 1) * 4) + quad) ^ (p & 7));
            bh[ni] = *(const shortx8*)&Xh_l[(p * 24 + vp) * 8];
        }
        #pragma unroll
        for (int mi = 0; mi < 3; ++mi)
            #pragma unroll
            for (int ni = 0; ni < 4; ++ni)
                acc[mi][ni] = __builtin_amdgcn_mfma_f32_16x16x32_bf16(ah[mi], bh[ni], acc[mi][ni], 0, 0, 0);
    }

    const float* bias = (mat == 0) ? bq : (mat == 1) ? bk : bv;
    short* Y = (mat == 0) ? Qb : (mat == 1) ? Kb : Vb;

    __syncthreads();   // all frag reads of Xh_l done before overlay

    if (mat < 2) {
        // ---- Q/K: LDS [p][o stride 200], then coalesced [w][d] rows ----
        short* T = (short*)smem;   // 64*200*2 = 25600 B
        #pragma unroll
        for (int mi = 0; mi < 3; ++mi) {
            float4 b4 = *(const float4*)&bias[g * CG + ob + mi * 16 + quad * 4];
            const int o = ob + mi * 16 + quad * 4;
            #pragma unroll
            for (int ni = 0; ni < 4; ++ni) {
                const int p = ni * 16 + l15;
                T[p * 200 + o]     = f2bf(acc[mi][ni][0] + b4.x);
                T[p * 200 + o + 1] = f2bf(acc[mi][ni][1] + b4.y);
                T[p * 200 + o + 2] = f2bf(acc[mi][ni][2] + b4.z);
                T[p * 200 + o + 3] = f2bf(acc[mi][ni][3] + b4.w);
            }
        }
        __syncthreads();
        #pragma unroll
        for (int hc = 0; hc < HPG; ++hc) {
            const size_t nh = (size_t)n * HH + g * HPG + hc;
            #pragma unroll
            for (int half = 0; half < 2; ++half) {
                const int idx = tid + half * 256;
                const int p  = idx >> 3;
                const int dc = (idx & 7) * 8;
                *(shortx8*)&Y[(nh * WW + p0 + p) * DD + dc] =
                    *(const shortx8*)&T[p * 200 + hc * 64 + dc];
            }
        }
    } else {
        // ---- V: LDS [o][p stride 68], then coalesced [d][w] rows ----
        short* T = (short*)smem;   // 192*68*2 = 26112 B
        #pragma unroll
        for (int mi = 0; mi < 3; ++mi) {
            float4 b4 = *(const float4*)&bias[g * CG + ob + mi * 16 + quad * 4];
            const int o = ob + mi * 16 + quad * 4;
            #pragma unroll
            for (int ni = 0; ni < 4; ++ni) {
                const int p = ni * 16 + l15;
                T[(o)     * 68 + p] = f2bf(acc[mi][ni][0] + b4.x);
                T[(o + 1) * 68 + p] = f2bf(acc[mi][ni][1] + b4.y);
                T[(o + 2) * 68 + p] = f2bf(acc[mi][ni][2] + b4.z);
                T[(o + 3) * 68 + p] = f2bf(acc[mi][ni][3] + b4.w);
            }
        }
        __syncthreads();
        #pragma unroll
        for (int pass = 0; pass < 6; ++pass) {
            const int idx = tid + pass * 256;
            const int o  = idx >> 3;
            const int pc = (idx & 7) * 8;
            const size_t nh = (size_t)n * HH + g * HPG + (o >> 6);
            const int d = o & 63;
            *(shortx8*)&Y[(nh * DD + d) * WW + p0 + pc] =
                *(const shortx8*)&T[o * 68 + pc];
        }
    }
}

// ---------------------------------------------------------------------------
// Attention (unchanged from R9/R10: full-K, LDS-staged, fused epilogue).
// grid: 1536 1-D blocks (XCD swizzle: 6 (n,h) pairs per XCD), block 256.
// ---------------------------------------------------------------------------
#define PST 72
#define RST 65

__global__ __launch_bounds__(256) void attn_split(
    const short* __restrict__ Qb, const short* __restrict__ Kb,
    const short* __restrict__ Vb, const float* __restrict__ mask,
    float* __restrict__ out)
{
    __shared__ __align__(16) char smem[33792];
    short* Ks_l = (short*)smem;              // 8192 B [key][d] swizzled
    short* Vs_l = (short*)(smem + 8192);     // 8192 B [d][key] swizzled
    short* Pl   = (short*)(smem + 16384);    // 9216 B wave-private P strips
    float* Ml   = (float*)(smem + 25600);    // 8192 B pre-transformed mask

    const int lin  = blockIdx.x;
    const int xcd  = lin & 7;
    const int slot = lin >> 3;               // 0..191
    const int pair = xcd * 6 + (slot >> 5);  // 0..47
    const int qt   = slot & 31;
    const int n    = pair / HH;
    const int h    = pair % HH;
    const int q0   = qt * 64;

    const int tid  = threadIdx.x;
    const int wid  = __builtin_amdgcn_readfirstlane(tid >> 6);
    const int lane = tid & 63;
    const int l15  = lane & 15;
    const int quad = lane >> 4;

    const size_t nh = (size_t)n * HH + h;
    const short* Kbase = Kb + nh * WW * DD;   // [key][d]
    const short* Vbase = Vb + nh * DD * WW;   // [d][w]

    {
        const float* mbase = mask + (size_t)n * WW;
        #pragma unroll
        for (int i = 0; i < WW / 256; ++i)
            Ml[tid + i * 256] = fmaf(mbase[tid + i * 256], L2E, -MSH);
    }

    shortx8 qf[2];
    {
        const short* qp = Qb + (nh * WW + q0 + wid * 16 + l15) * DD + quad * 8;
        qf[0] = *(const shortx8*)(qp);
        qf[1] = *(const shortx8*)(qp + 32);
    }

    floatx4 oacc[4];
    #pragma unroll
    for (int nn2 = 0; nn2 < 4; ++nn2) oacc[nn2] = (floatx4)0.0f;
    float lst[4] = {0.f, 0.f, 0.f, 0.f};

    short* Pw = Pl + wid * 16 * PST;

    for (int kt = 0; kt < WW / 64; ++kt) {
        const int k0 = kt * 64;

        #pragma unroll
        for (int t = 0; t < 2; ++t) {
            const int R  = wid * 16 + t * 8;           // uniform
            const int r  = R + (lane >> 3);
            const int cg = (lane & 7) ^ (r & 7);       // swizzled source chunk
            gl_lds16(Kbase + (size_t)(k0 + r) * DD + cg * 8, &Ks_l[R * 64]);
            gl_lds16(Vbase + (size_t)r * WW + k0 + cg * 8, &Vs_l[R * 64]);
        }
        __syncthreads();

        shortx8 kf[4][2], vf[4][2];
        #pragma unroll
        for (int jj = 0; jj < 4; ++jj) {
            const int r = 16 * jj + l15;
            #pragma unroll
            for (int hf = 0; hf < 2; ++hf)
                kf[jj][hf] = *(const shortx8*)&Ks_l[r * 64 + (((hf * 4 + quad) ^ (r & 7)) * 8)];
        }
        #pragma unroll
        for (int nn2 = 0; nn2 < 4; ++nn2) {
            const int r = 16 * nn2 + l15;
            #pragma unroll
            for (int hf = 0; hf < 2; ++hf)
                vf[nn2][hf] = *(const shortx8*)&Vs_l[r * 64 + (((hf * 4 + quad) ^ (r & 7)) * 8)];
        }
        float mv2[4];
        #pragma unroll
        for (int jj = 0; jj < 4; ++jj)
            mv2[jj] = Ml[k0 + 16 * jj + l15];

        floatx4 sacc[4];
        #pragma unroll
        for (int jj = 0; jj < 4; ++jj) {
            sacc[jj] = (floatx4)0.0f;
            sacc[jj] = __builtin_amdgcn_mfma_f32_16x16x32_bf16(qf[0], kf[jj][0], sacc[jj], 0, 0, 0);
            sacc[jj] = __builtin_amdgcn_mfma_f32_16x16x32_bf16(qf[1], kf[jj][1], sacc[jj], 0, 0, 0);
        }

        #pragma unroll
        for (int jj = 0; jj < 4; ++jj) {
            #pragma unroll
            for (int r = 0; r < 4; ++r) {
                float p = fast_exp2(fmaf(sacc[jj][r], C18, mv2[jj]));
                lst[r] += p;
                Pw[(quad * 4 + r) * PST + 16 * jj + l15] = f2bf(p);
            }
        }

        shortx8 pf0 = *(const shortx8*)&Pw[l15 * PST + quad * 8];
        shortx8 pf1 = *(const shortx8*)&Pw[l15 * PST + 32 + quad * 8];

        #pragma unroll
        for (int nn2 = 0; nn2 < 4; ++nn2) {
            oacc[nn2] = __builtin_amdgcn_mfma_f32_16x16x32_bf16(pf0, vf[nn2][0], oacc[nn2], 0, 0, 0);
            oacc[nn2] = __builtin_amdgcn_mfma_f32_16x16x32_bf16(pf1, vf[nn2][1], oacc[nn2], 0, 0, 0);
        }
        __syncthreads();
    }

    float linv[4];
    #pragma unroll
    for (int r = 0; r < 4; ++r) linv[r] = 1.0f / rsum16(lst[r]);

    float* Ol = (float*)smem;
    #pragma unroll
    for (int nn2 = 0; nn2 < 4; ++nn2)
        #pragma unroll
        for (int r = 0; r < 4; ++r)
            Ol[(wid * 16 + quad * 4 + r) * RST + nn2 * 16 + l15] = oacc[nn2][r] * linv[r];
    __syncthreads();

    float* obase = out + (nh * DD) * WW + q0;
    #pragma unroll
    for (int it = 0; it < 4; ++it) {
        const int idx = tid + it * 256;
        const int q4 = (idx & 15) * 4;
        const int d  = idx >> 4;
        floatx4 v;
        #pragma unroll
        for (int i = 0; i < 4; ++i) v[i] = Ol[(q4 + i) * RST + d];
        *(floatx4*)&obase[(size_t)d * WW + q4] = v;
    }
}

// ---------------------------------------------------------------------------
extern "C" void kernel_launch(void* const* d_in, const int* in_sizes, int n_in,
                              void* d_out, int out_size, void* d_ws, size_t ws_size,
                              hipStream_t stream) {
    const float* x    = (const float*)d_in[0];
    const float* mask = (const float*)d_in[1];
    const float* wq   = (const float*)d_in[2];
    const float* bq   = (const float*)d_in[3];
    const float* wk   = (const float*)d_in[4];
    const float* bk   = (const float*)d_in[5];
    const float* wv   = (const float*)d_in[6];
    const float* bv   = (const float*)d_in[7];
    float* out = (float*)d_out;

    const size_t per = (size_t)NB * HH * WW * DD;   // 6,291,456
    short* Qb  = (short*)d_ws;
    short* Kb  = Qb + per;
    short* Vb  = Kb + per;
    short* XTh = Vb + per;
    short* Wfp = XTh + per;                          // 3*WSZ shorts

    hipLaunchKernelGGL(prep, dim3(1536 + WSZ / 256), dim3(256), 0, stream,
                       x, wq, wk, wv, XTh, Wfp);
    hipLaunchKernelGGL(qkv_gemm, dim3(1536), dim3(256), 0, stream,
                       XTh, Wfp, bq, bk, bv, Qb, Kb, Vb);
    hipLaunchKernelGGL(attn_split, dim3(1536), dim3(256), 0, stream,
                       Qb, Kb, Vb, mask, out);
}

// Round 12
// 194.853 us; speedup vs baseline: 2.7707x; 1.0241x over previous
//
#include <hip/hip_runtime.h>
#include <math.h>

typedef __attribute__((ext_vector_type(4))) float floatx4;
typedef __attribute__((ext_vector_type(8))) short shortx8;   // 8 bf16
typedef __attribute__((ext_vector_type(4))) short shortx4;   // 4 bf16 (8B)

#define NB 4
#define CC 768
#define WW 2048
#define HH 12
#define DD 64
#define GG 4
#define CG 192
#define HPG 3
#define L2E 1.4426950408889634f
#define C18 0.18033688011112043f   // 0.125 * log2(e)
#define MSH 11.541560327111707f    // 8.0 * log2(e)  (fixed softmax shift)
#define WSZ (GG * CG * CG)         // 147456

__device__ __forceinline__ float fast_exp2(float x) {
    return __builtin_amdgcn_exp2f(x);   // v_exp_f32 (log2 domain)
}

__device__ __forceinline__ short f2bf(float f) {
    union { float f; unsigned u; } v; v.f = f;
    unsigned r = v.u + 0x7fffu + ((v.u >> 16) & 1u);   // RNE
    return (short)(r >> 16);
}

template<int CTRL>
__device__ __forceinline__ float dppror(float v) {
    return __int_as_float(__builtin_amdgcn_update_dpp(
        0, __float_as_int(v), CTRL, 0xf, 0xf, false));
}
__device__ __forceinline__ float rsum16(float v) {   // 16-lane DPP-row sum
    v += dppror<0x128>(v);
    v += dppror<0x124>(v);
    v += dppror<0x122>(v);
    v += dppror<0x121>(v);
    return v;
}

// async global->LDS, 16B per lane; lds base must be wave-uniform
__device__ __forceinline__ void gl_lds16(const void* g, void* l) {
    __builtin_amdgcn_global_load_lds(
        (const __attribute__((address_space(1))) unsigned int*)g,
        (__attribute__((address_space(3))) unsigned int*)l, 16, 0, 0);
}

// ---------------------------------------------------------------------------
// Prep (merged): blocks [0,1536): x -> XTh [N,W,C] bf16 (LDS-transposed,
// coalesced both ways). blocks [1536,2112): weights -> Wf fragment-major.
// ---------------------------------------------------------------------------
__global__ __launch_bounds__(256) void prep(
    const float* __restrict__ x,
    const float* __restrict__ wq, const float* __restrict__ wk,
    const float* __restrict__ wv,
    short* __restrict__ XTh, short* __restrict__ Wf)
{
    __shared__ short Th[64 * 72];
    const int tid = threadIdx.x;
    const int b   = blockIdx.x;

    if (b < 1536) {
        const int w0 = (b & 31) * 64;
        const int c0 = ((b >> 5) % 12) * 64;
        const int n  = b / 384;
        const int w  = tid & 63;
        const int cb = (tid >> 6) * 16;

        float xv[16];
        #pragma unroll
        for (int j = 0; j < 16; ++j)
            xv[j] = x[((size_t)n * CC + c0 + cb + j) * WW + w0 + w];

        shortx8 hi0, hi1;
        #pragma unroll
        for (int j = 0; j < 8; ++j) { hi0[j] = f2bf(xv[j]); hi1[j] = f2bf(xv[j + 8]); }
        *(shortx8*)&Th[w * 72 + cb]     = hi0;
        *(shortx8*)&Th[w * 72 + cb + 8] = hi1;
        __syncthreads();

        const int wr = tid >> 2;
        const int cc = (tid & 3) * 16;
        const size_t ro = ((size_t)n * WW + w0 + wr) * CC + c0 + cc;
        *(shortx8*)&XTh[ro]     = *(const shortx8*)&Th[wr * 72 + cc];
        *(shortx8*)&XTh[ro + 8] = *(const shortx8*)&Th[wr * 72 + cc + 8];
    } else {
        const int t = (b - 1536) * 256 + tid;          // < WSZ
        const int g  = t / (CG * CG);
        const int r  = t - g * (CG * CG);
        const int o  = r / CG;
        const int k  = r - o * CG;
        const int off = (((g * 12 + (o >> 4)) * 6 + (k >> 5)) * 512)
                      + ((k >> 3) & 3) * 128 + (o & 15) * 8 + (k & 7);
        const float* src[3] = {wq, wk, wv};
        #pragma unroll
        for (int m = 0; m < 3; ++m)
            Wf[m * WSZ + off] = f2bf(src[m][t]);
    }
}

// ---------------------------------------------------------------------------
// Grouped 1x1 conv as single-bf16 MFMA GEMM (unchanged from R11).
// grid: 1536 1-D blocks, block 256.
// ---------------------------------------------------------------------------
__global__ __launch_bounds__(256) void qkv_gemm(
    const short* __restrict__ XTh, const short* __restrict__ Wf,
    const float* __restrict__ bq, const float* __restrict__ bk,
    const float* __restrict__ bv,
    short* __restrict__ Qb, short* __restrict__ Kb, short* __restrict__ Vb)
{
    __shared__ __align__(16) char smem[26112];
    short* Xh_l = (short*)smem;              // 24576 B, [p][24 chunks] swz

    const int lin  = blockIdx.x;
    const int xcd  = lin & 7;
    const int iw   = lin >> 3;              // 0..191
    const int mat  = iw % 3;
    const int tile = (iw / 3) * 8 + xcd;    // 0..511
    const int p0   = (tile & 31) * 64;
    const int g    = (tile >> 5) & 3;
    const int n    = tile >> 7;

    const int tid  = threadIdx.x;
    const int wid  = __builtin_amdgcn_readfirstlane(tid >> 6);
    const int lane = tid & 63;
    const int l15  = lane & 15;
    const int quad = lane >> 4;
    const int ob   = wid * 48;

    {
        const short* xhb = XTh + ((size_t)n * WW + p0) * CC + g * CG;
        #pragma unroll
        for (int rd = 0; rd < 6; ++rd) {
            const int Lb = rd * 256 + wid * 64;           // wave-uniform
            const int L  = Lb + lane;
            const int p  = (L * 2731) >> 16;              // L / 24
            const int sc = L - p * 24;
            const int ss = (sc & ~7) | ((sc & 7) ^ (p & 7));
            gl_lds16(xhb + (size_t)p * CC + ss * 8, &Xh_l[Lb * 8]);
        }
    }
    __syncthreads();

    floatx4 acc[3][4];
    #pragma unroll
    for (int mi = 0; mi < 3; ++mi)
        #pragma unroll
        for (int ni = 0; ni < 4; ++ni) acc[mi][ni] = (floatx4)0.0f;

    const short* wfm = Wf + (size_t)mat * WSZ + lane * 8;

    #pragma unroll
    for (int ks = 0; ks < 6; ++ks) {
        shortx8 ah[3], bh[4];
        #pragma unroll
        for (int mi = 0; mi < 3; ++mi)
            ah[mi] = *(const shortx8*)(wfm + (((g * 12 + wid * 3 + mi) * 6 + ks) << 9));
        #pragma unroll
        for (int ni = 0; ni < 4; ++ni) {
            const int p  = ni * 16 + l15;
            const int vp = (ks >> 1) * 8 + ((((ks & 1) * 4) + quad) ^ (p & 7));
            bh[ni] = *(const shortx8*)&Xh_l[(p * 24 + vp) * 8];
        }
        #pragma unroll
        for (int mi = 0; mi < 3; ++mi)
            #pragma unroll
            for (int ni = 0; ni < 4; ++ni)
                acc[mi][ni] = __builtin_amdgcn_mfma_f32_16x16x32_bf16(ah[mi], bh[ni], acc[mi][ni], 0, 0, 0);
    }

    const float* bias = (mat == 0) ? bq : (mat == 1) ? bk : bv;
    short* Y = (mat == 0) ? Qb : (mat == 1) ? Kb : Vb;

    __syncthreads();   // all frag reads of Xh_l done before overlay

    if (mat < 2) {
        short* T = (short*)smem;   // 64*200*2 = 25600 B
        #pragma unroll
        for (int mi = 0; mi < 3; ++mi) {
            float4 b4 = *(const float4*)&bias[g * CG + ob + mi * 16 + quad * 4];
            const int o = ob + mi * 16 + quad * 4;
            #pragma unroll
            for (int ni = 0; ni < 4; ++ni) {
                const int p = ni * 16 + l15;
                T[p * 200 + o]     = f2bf(acc[mi][ni][0] + b4.x);
                T[p * 200 + o + 1] = f2bf(acc[mi][ni][1] + b4.y);
                T[p * 200 + o + 2] = f2bf(acc[mi][ni][2] + b4.z);
                T[p * 200 + o + 3] = f2bf(acc[mi][ni][3] + b4.w);
            }
        }
        __syncthreads();
        #pragma unroll
        for (int hc = 0; hc < HPG; ++hc) {
            const size_t nh = (size_t)n * HH + g * HPG + hc;
            #pragma unroll
            for (int half = 0; half < 2; ++half) {
                const int idx = tid + half * 256;
                const int p  = idx >> 3;
                const int dc = (idx & 7) * 8;
                *(shortx8*)&Y[(nh * WW + p0 + p) * DD + dc] =
                    *(const shortx8*)&T[p * 200 + hc * 64 + dc];
            }
        }
    } else {
        short* T = (short*)smem;   // 192*68*2 = 26112 B
        #pragma unroll
        for (int mi = 0; mi < 3; ++mi) {
            float4 b4 = *(const float4*)&bias[g * CG + ob + mi * 16 + quad * 4];
            const int o = ob + mi * 16 + quad * 4;
            #pragma unroll
            for (int ni = 0; ni < 4; ++ni) {
                const int p = ni * 16 + l15;
                T[(o)     * 68 + p] = f2bf(acc[mi][ni][0] + b4.x);
                T[(o + 1) * 68 + p] = f2bf(acc[mi][ni][1] + b4.y);
                T[(o + 2) * 68 + p] = f2bf(acc[mi][ni][2] + b4.z);
                T[(o + 3) * 68 + p] = f2bf(acc[mi][ni][3] + b4.w);
            }
        }
        __syncthreads();
        #pragma unroll
        for (int pass = 0; pass < 6; ++pass) {
            const int idx = tid + pass * 256;
            const int o  = idx >> 3;
            const int pc = (idx & 7) * 8;
            const size_t nh = (size_t)n * HH + g * HPG + (o >> 6);
            const int d = o & 63;
            *(shortx8*)&Y[(nh * DD + d) * WW + p0 + pc] =
                *(const shortx8*)&T[o * 68 + pc];
        }
    }
}

// ---------------------------------------------------------------------------
// Attention v2: DOUBLE-BUFFERED LDS staging, ONE barrier per K-tile.
// Per iter: issue global_load_lds for tile kt+1 into buffer B, compute tile
// kt from buffer A, single __syncthreads() (drains B-loads after ~800 cyc of
// compute has hidden their latency + protects A for reuse).
// LDS 50176 B -> 3 blocks/CU. grid: 1536 1-D blocks (XCD swizzle), block 256.
// ---------------------------------------------------------------------------
#define PST 72
#define RST 65

__global__ __launch_bounds__(256) void attn_split(
    const short* __restrict__ Qb, const short* __restrict__ Kb,
    const short* __restrict__ Vb, const float* __restrict__ mask,
    float* __restrict__ out)
{
    __shared__ __align__(16) char smem[50176];
    // [0]:Ks0 8K [8192]:Ks1 8K [16384]:Vs0 8K [24576]:Vs1 8K
    // [32768]: Pl 9216  [41984]: Ml 8192
    short* Pl = (short*)(smem + 32768);
    float* Ml = (float*)(smem + 41984);

    const int lin  = blockIdx.x;
    const int xcd  = lin & 7;
    const int slot = lin >> 3;               // 0..191
    const int pair = xcd * 6 + (slot >> 5);  // 0..47
    const int qt   = slot & 31;
    const int n    = pair / HH;
    const int h    = pair % HH;
    const int q0   = qt * 64;

    const int tid  = threadIdx.x;
    const int wid  = __builtin_amdgcn_readfirstlane(tid >> 6);
    const int lane = tid & 63;
    const int l15  = lane & 15;
    const int quad = lane >> 4;

    const size_t nh = (size_t)n * HH + h;
    const short* Kbase = Kb + nh * WW * DD;   // [key][d]
    const short* Vbase = Vb + nh * DD * WW;   // [d][w]

    // stage pre-transformed mask once
    {
        const float* mbase = mask + (size_t)n * WW;
        #pragma unroll
        for (int i = 0; i < WW / 256; ++i)
            Ml[tid + i * 256] = fmaf(mbase[tid + i * 256], L2E, -MSH);
    }

    shortx8 qf[2];
    {
        const short* qp = Qb + (nh * WW + q0 + wid * 16 + l15) * DD + quad * 8;
        qf[0] = *(const shortx8*)(qp);
        qf[1] = *(const shortx8*)(qp + 32);
    }

    floatx4 oacc[4];
    #pragma unroll
    for (int nn2 = 0; nn2 < 4; ++nn2) oacc[nn2] = (floatx4)0.0f;
    float lst[4] = {0.f, 0.f, 0.f, 0.f};

    short* Pw = Pl + wid * 16 * PST;

    // hoisted staging addresses (per lane, advance per tile)
    const int r0  = wid * 16 + (lane >> 3);
    const int r1  = r0 + 8;
    const int cg0 = (lane & 7) ^ (r0 & 7);
    const int cg1 = (lane & 7) ^ (r1 & 7);
    const short* kp0 = Kbase + (size_t)r0 * DD + cg0 * 8;   // += 64*DD/tile
    const short* kp1 = Kbase + (size_t)r1 * DD + cg1 * 8;
    const short* vp0 = Vbase + (size_t)r0 * WW + cg0 * 8;   // += 64/tile
    const short* vp1 = Vbase + (size_t)r1 * WW + cg1 * 8;
    const int KR0 = (wid * 16) * 64, KR1 = (wid * 16 + 8) * 64;   // LDS offs

    #define STAGE(j, bb)                                                      \
        do {                                                                  \
            short* ksd = (short*)(smem + (bb) * 8192);                        \
            short* vsd = (short*)(smem + 16384 + (bb) * 8192);                \
            gl_lds16(kp0 + (size_t)(j) * 64 * DD, ksd + KR0);                 \
            gl_lds16(kp1 + (size_t)(j) * 64 * DD, ksd + KR1);                 \
            gl_lds16(vp0 + (j) * 64, vsd + KR0);                              \
            gl_lds16(vp1 + (j) * 64, vsd + KR1);                              \
        } while (0)

    STAGE(0, 0);
    __syncthreads();   // tile 0 ready (also covers Ml)

    for (int kt = 0; kt < WW / 64; ++kt) {
        const int bb = kt & 1;
        if (kt + 1 < WW / 64) STAGE(kt + 1, 1 - bb);

        const short* Ks_l = (const short*)(smem + bb * 8192);
        const short* Vs_l = (const short*)(smem + 16384 + bb * 8192);
        const int k0 = kt * 64;

        shortx8 kf[4][2], vf[4][2];
        #pragma unroll
        for (int jj = 0; jj < 4; ++jj) {
            const int r = 16 * jj + l15;
            #pragma unroll
            for (int hf = 0; hf < 2; ++hf)
                kf[jj][hf] = *(const shortx8*)&Ks_l[r * 64 + (((hf * 4 + quad) ^ (r & 7)) * 8)];
        }
        #pragma unroll
        for (int nn2 = 0; nn2 < 4; ++nn2) {
            const int r = 16 * nn2 + l15;
            #pragma unroll
            for (int hf = 0; hf < 2; ++hf)
                vf[nn2][hf] = *(const shortx8*)&Vs_l[r * 64 + (((hf * 4 + quad) ^ (r & 7)) * 8)];
        }
        float mv2[4];
        #pragma unroll
        for (int jj = 0; jj < 4; ++jj)
            mv2[jj] = Ml[k0 + 16 * jj + l15];

        floatx4 sacc[4];
        #pragma unroll
        for (int jj = 0; jj < 4; ++jj) {
            sacc[jj] = (floatx4)0.0f;
            sacc[jj] = __builtin_amdgcn_mfma_f32_16x16x32_bf16(qf[0], kf[jj][0], sacc[jj], 0, 0, 0);
            sacc[jj] = __builtin_amdgcn_mfma_f32_16x16x32_bf16(qf[1], kf[jj][1], sacc[jj], 0, 0, 0);
        }

        #pragma unroll
        for (int jj = 0; jj < 4; ++jj) {
            #pragma unroll
            for (int r = 0; r < 4; ++r) {
                float p = fast_exp2(fmaf(sacc[jj][r], C18, mv2[jj]));
                lst[r] += p;
                Pw[(quad * 4 + r) * PST + 16 * jj + l15] = f2bf(p);
            }
        }

        shortx8 pf0 = *(const shortx8*)&Pw[l15 * PST + quad * 8];
        shortx8 pf1 = *(const shortx8*)&Pw[l15 * PST + 32 + quad * 8];

        #pragma unroll
        for (int nn2 = 0; nn2 < 4; ++nn2) {
            oacc[nn2] = __builtin_amdgcn_mfma_f32_16x16x32_bf16(pf0, vf[nn2][0], oacc[nn2], 0, 0, 0);
            oacc[nn2] = __builtin_amdgcn_mfma_f32_16x16x32_bf16(pf1, vf[nn2][1], oacc[nn2], 0, 0, 0);
        }
        __syncthreads();   // drains next-tile loads + protects bb for reuse
    }
    #undef STAGE

    float linv[4];
    #pragma unroll
    for (int r = 0; r < 4; ++r) linv[r] = 1.0f / rsum16(lst[r]);

    float* Ol = (float*)smem;
    #pragma unroll
    for (int nn2 = 0; nn2 < 4; ++nn2)
        #pragma unroll
        for (int r = 0; r < 4; ++r)
            Ol[(wid * 16 + quad * 4 + r) * RST + nn2 * 16 + l15] = oacc[nn2][r] * linv[r];
    __syncthreads();

    float* obase = out + (nh * DD) * WW + q0;
    #pragma unroll
    for (int it = 0; it < 4; ++it) {
        const int idx = tid + it * 256;
        const int q4 = (idx & 15) * 4;
        const int d  = idx >> 4;
        floatx4 v;
        #pragma unroll
        for (int i = 0; i < 4; ++i) v[i] = Ol[(q4 + i) * RST + d];
        *(floatx4*)&obase[(size_t)d * WW + q4] = v;
    }
}

// ---------------------------------------------------------------------------
extern "C" void kernel_launch(void* const* d_in, const int* in_sizes, int n_in,
                              void* d_out, int out_size, void* d_ws, size_t ws_size,
                              hipStream_t stream) {
    const float* x    = (const float*)d_in[0];
    const float* mask = (const float*)d_in[1];
    const float* wq   = (const float*)d_in[2];
    const float* bq   = (const float*)d_in[3];
    const float* wk   = (const float*)d_in[4];
    const float* bk   = (const float*)d_in[5];
    const float* wv   = (const float*)d_in[6];
    const float* bv   = (const float*)d_in[7];
    float* out = (float*)d_out;

    const size_t per = (size_t)NB * HH * WW * DD;   // 6,291,456
    short* Qb  = (short*)d_ws;
    short* Kb  = Qb + per;
    short* Vb  = Kb + per;
    short* XTh = Vb + per;
    short* Wfp = XTh + per;                          // 3*WSZ shorts

    hipLaunchKernelGGL(prep, dim3(1536 + WSZ / 256), dim3(256), 0, stream,
                       x, wq, wk, wv, XTh, Wfp);
    hipLaunchKernelGGL(qkv_gemm, dim3(1536), dim3(256), 0, stream,
                       XTh, Wfp, bq, bk, bv, Qb, Kb, Vb);
    hipLaunchKernelGGL(attn_split, dim3(1536), dim3(256), 0, stream,
                       Qb, Kb, Vb, mask, out);
}